// Round 9
// baseline (4289.028 us; speedup 1.0000x reference)
//
#include <hip/hip_runtime.h>

// GRU-D, round 9.
// pack -> prepass (gamma_x f32, gamma_h bf16) -> grud_rec9.
// rec9 = rec8 + register-resident W_h[0]/W_h[2] done correctly:
//   - 32 INDIVIDUALLY NAMED bf8_t fragments (no arrays, no alloca),
//   - amdgpu_waves_per_eu(2,2) -> 256-VGPR budget (free: LDS caps 1 blk/CU),
//   - KEEPV pins inside the t-loop prevent rematerialization,
//   - LDS = W_h[1] (131072 B) + state (28928 B) = 160000 B (fits; the R6/R7
//     failures were an LDS-size arithmetic error, not promote-alloca).
// The z/r and h~ MFMA chains then read only registers + LDS — no L2 loads
// on the recurrence critical path.

constexpr int Bn = 512, Tn = 256, Dn = 64, Hn = 256;
constexpr int BB = 16, NBLK = Bn / BB;   // 32 blocks

typedef __attribute__((ext_vector_type(8))) short bf8_t;
typedef __attribute__((ext_vector_type(4))) float f4_t;

constexpr size_t OFF_WH  = 0;
constexpr size_t OFF_WX  = 196608;
constexpr size_t OFF_WM  = 245760;
constexpr size_t OFF_WGH = 294912;
constexpr size_t OFF_WGX = 311296;
constexpr int    PACK_SLOTS = 39424;

constexpr size_t GX_OFF  = (size_t)1 << 20;
constexpr size_t GH_OFF  = GX_OFF + (size_t)Bn * Tn * Dn * 4;
constexpr size_t WS_NEED = GH_OFF + (size_t)Bn * Tn * Hn * 2;    // 101,711,872

__device__ __forceinline__ unsigned short f2bf(float x) {
    union { float f; unsigned int u; } v; v.f = x;
    unsigned int r = (v.u + 0x7fffu + ((v.u >> 16) & 1u)) >> 16;   // RNE
    return (unsigned short)r;
}
__device__ __forceinline__ float bf2f(unsigned short u) {
    union { unsigned int i; float f; } v; v.i = ((unsigned int)u) << 16; return v.f;
}
__device__ __forceinline__ bf8_t LD8(const short* p) { return *(const bf8_t*)p; }
__device__ __forceinline__ f4_t MF(bf8_t a, bf8_t b, f4_t c) {
    return __builtin_amdgcn_mfma_f32_16x16x32_bf16(a, b, c, 0, 0, 0);
}
__device__ __forceinline__ f4_t MFp(bf8_t a, const short* bp, f4_t c) {
    return MF(a, LD8(bp), c);
}
__device__ __forceinline__ const short* BA(const short* p, int ntG, int KT, int kt, int lane) {
    return p + (((size_t)ntG * KT + kt) * 64 + lane) * 8;
}
// LDS-only barrier: drains LDS ops, leaves global (vmcnt) loads in flight.
__device__ __forceinline__ void lds_sync() {
    __builtin_amdgcn_sched_barrier(0);
    asm volatile("s_waitcnt lgkmcnt(0)" ::: "memory");
    __builtin_amdgcn_s_barrier();
    __builtin_amdgcn_sched_barrier(0);
}
#define KV(x) asm volatile("" : "+v"(x))

// ---------------------------------------------------------------------------
// pack_weights (unchanged, proven)
// ---------------------------------------------------------------------------
__global__ __launch_bounds__(256) void pack_weights(
    const float* __restrict__ W_gx, const float* __restrict__ W_gh,
    const float* __restrict__ W_x,  const float* __restrict__ W_h,
    const float* __restrict__ W_m,  short* __restrict__ out)
{
    const int slot = blockIdx.x * 256 + threadIdx.x;
    if (slot >= PACK_SLOTS) return;

    const float* w; int ldn, l, kt, j, kbase;
    if (slot < 24576) {
        int g = slot >> 13, rem = slot & 8191;
        int ntG = rem >> 9, r2 = rem & 511;
        kt = r2 >> 6; l = r2 & 63;
        j = ntG * 16 + (l & 15);
        w = W_h + (size_t)g * Hn * Hn; ldn = Hn;
    } else if (slot < 30720) {
        int s = slot - 24576;
        int g = s >> 11, rem = s & 2047;
        int ntG = rem >> 7, r2 = rem & 127;
        kt = r2 >> 6; l = r2 & 63;
        j = ntG * 16 + (l & 15);
        w = W_x + (size_t)g * Dn * Hn; ldn = Hn;
    } else if (slot < 36864) {
        int s = slot - 30720;
        int g = s >> 11, rem = s & 2047;
        int ntG = rem >> 7, r2 = rem & 127;
        kt = r2 >> 6; l = r2 & 63;
        j = ntG * 16 + (l & 15);
        w = W_m + (size_t)g * Dn * Hn; ldn = Hn;
    } else if (slot < 38912) {
        int s = slot - 36864;
        int ntG = s >> 7, r2 = s & 127;
        kt = r2 >> 6; l = r2 & 63;
        j = ntG * 16 + (l & 15);
        w = W_gh; ldn = Hn;
    } else {
        int s = slot - 38912;
        int ntG = s >> 7, r2 = s & 127;
        kt = r2 >> 6; l = r2 & 63;
        j = ntG * 16 + (l & 15);
        w = W_gx; ldn = Dn;
    }
    kbase = kt * 32 + ((l >> 4) << 3);
    bf8_t v;
    #pragma unroll
    for (int i = 0; i < 8; ++i)
        v[i] = (short)f2bf(w[(size_t)(kbase + i) * ldn + j]);
    *(bf8_t*)&out[(size_t)slot * 8] = v;
}

// ---------------------------------------------------------------------------
// prepass (unchanged, proven)
// ---------------------------------------------------------------------------
__global__ __launch_bounds__(256) void grud_prepass(
    const float* __restrict__ Dl, const float* __restrict__ b_gx,
    const float* __restrict__ b_gh, const short* __restrict__ pk,
    float* __restrict__ gx, unsigned short* __restrict__ gh)
{
    __shared__ short sDf[2 * 64 * 8];
    const int tid = threadIdx.x, w = tid >> 6, lane = tid & 63;
    const int bt = blockIdx.x >> 8, t = blockIdx.x & 255;
    const int b0 = bt * 16;
    const int c15 = lane & 15, rowb = (lane >> 4) * 4;

    if (w < 2) {
        const int row = lane & 15, cb = w * 32 + ((lane >> 4) << 3);
        const float* p = Dl + ((size_t)(b0 + row) * Tn + t) * Dn + cb;
        float4 a = *(const float4*)p, b = *(const float4*)(p + 4);
        bf8_t v;
        v[0]=(short)f2bf(a.x); v[1]=(short)f2bf(a.y); v[2]=(short)f2bf(a.z); v[3]=(short)f2bf(a.w);
        v[4]=(short)f2bf(b.x); v[5]=(short)f2bf(b.y); v[6]=(short)f2bf(b.z); v[7]=(short)f2bf(b.w);
        *(bf8_t*)&sDf[(w * 64 + lane) * 8] = v;
    }
    __syncthreads();
    bf8_t df0 = *(const bf8_t*)&sDf[lane * 8];
    bf8_t df1 = *(const bf8_t*)&sDf[(64 + lane) * 8];

    #pragma unroll
    for (int i = 0; i < 4; ++i) {
        const int ntG = 4 * w + i;
        f4_t acc = {0.f, 0.f, 0.f, 0.f};
        acc = MFp(df0, BA(pk + OFF_WGH, ntG, 2, 0, lane), acc);
        acc = MFp(df1, BA(pk + OFF_WGH, ntG, 2, 1, lane), acc);
        const int col = ntG * 16 + c15;
        const float bb = b_gh[col];
        #pragma unroll
        for (int q = 0; q < 4; ++q) {
            const int r = rowb + q;
            gh[((size_t)(b0 + r) * Tn + t) * Hn + col] =
                f2bf(__expf(-fmaxf(acc[q] + bb, 0.f)));
        }
    }
    {
        f4_t acc = {0.f, 0.f, 0.f, 0.f};
        acc = MFp(df0, BA(pk + OFF_WGX, w, 2, 0, lane), acc);
        acc = MFp(df1, BA(pk + OFF_WGX, w, 2, 1, lane), acc);
        const int col = w * 16 + c15;
        const float bb = b_gx[col];
        #pragma unroll
        for (int q = 0; q < 4; ++q) {
            const int r = rowb + q;
            gx[((size_t)(b0 + r) * Tn + t) * Dn + col] =
                __expf(-fmaxf(acc[q] + bb, 0.f));
        }
    }
}

// ---------------------------------------------------------------------------
// grud_rec9: fused recurrence, named-register-resident W_h[0]/W_h[2].
// ---------------------------------------------------------------------------
__global__ __attribute__((amdgpu_flat_work_group_size(512, 512), amdgpu_waves_per_eu(2, 2)))
void grud_rec9(
    const float* __restrict__ X, const float* __restrict__ M,
    const float* __restrict__ x_mean, const float* __restrict__ b_g,
    const float* __restrict__ W_cls, const float* __restrict__ b_cls,
    const short* __restrict__ pk, const float* __restrict__ gx,
    const unsigned short* __restrict__ gh, float* __restrict__ out)
{
    __shared__ short sWh1[16 * 8 * 64 * 8];      // 131072 B : W_h[1] B-frags
    __shared__ unsigned short sh_hb[16][264];    //   8448 B : h state (bf16)
    __shared__ short sA_xh[2 * 64 * 8];          //   2048 B
    __shared__ short sA_m [2 * 64 * 8];          //   2048 B
    __shared__ short sA_hd[8 * 64 * 8];          //   8192 B
    __shared__ short sA_rhd[8 * 64 * 8];         //   8192 B  => 160000 B

    const int tid = threadIdx.x, w = tid >> 6, lane = tid & 63;
    const int c15 = lane & 15, rowb = (lane >> 4) * 4;
    const int b0 = blockIdx.x * BB;

    // ---- resident W_h[0] (z) and W_h[2] (h~): 32 named frags = 128 VGPR ----
#define DWHZ(NT,KT) bf8_t whz##NT##_##KT = LD8(BA(pk + OFF_WH,           2*w+NT, 8, KT, lane));
#define DWHH(NT,KT) bf8_t whh##NT##_##KT = LD8(BA(pk + OFF_WH + 2*65536, 2*w+NT, 8, KT, lane));
    DWHZ(0,0) DWHZ(0,1) DWHZ(0,2) DWHZ(0,3) DWHZ(0,4) DWHZ(0,5) DWHZ(0,6) DWHZ(0,7)
    DWHZ(1,0) DWHZ(1,1) DWHZ(1,2) DWHZ(1,3) DWHZ(1,4) DWHZ(1,5) DWHZ(1,6) DWHZ(1,7)
    DWHH(0,0) DWHH(0,1) DWHH(0,2) DWHH(0,3) DWHH(0,4) DWHH(0,5) DWHH(0,6) DWHH(0,7)
    DWHH(1,0) DWHH(1,1) DWHH(1,2) DWHH(1,3) DWHH(1,4) DWHH(1,5) DWHH(1,6) DWHH(1,7)
#undef DWHZ
#undef DWHH

    for (int c = tid; c < 8192; c += 512)
        *(uint4*)&sWh1[c * 8] = *(const uint4*)&pk[OFF_WH + 65536 + (size_t)c * 8];
    for (int i = tid; i < 16 * 264; i += 512) (&sh_hb[0][0])[i] = 0;

    const float bz[2] = { b_g[0 * Hn + w * 32 + c15], b_g[0 * Hn + w * 32 + 16 + c15] };
    const float brr[2]= { b_g[1 * Hn + w * 32 + c15], b_g[1 * Hn + w * 32 + 16 + c15] };
    const float bh[2] = { b_g[2 * Hn + w * 32 + c15], b_g[2 * Hn + w * 32 + 16 + c15] };

    const int s    = w * 32 + (lane & 31);
    const int kt2  = s >> 7, fl = (s >> 1) & 63, half = s & 1;
    const int brow = fl & 15, bcol = kt2 * 32 + ((fl >> 4) << 3) + half * 4;
    const size_t brow_base = ((size_t)(b0 + brow) * Tn) * Dn + bcol;

    float xb[4] = {0.f, 0.f, 0.f, 0.f};
    float xp[4] = {0.f, 0.f, 0.f, 0.f};
    float4 mv, xv = {0,0,0,0}, gxv = {0,0,0,0};
    if (lane < 32) {
        xb[0]=x_mean[bcol]; xb[1]=x_mean[bcol+1]; xb[2]=x_mean[bcol+2]; xb[3]=x_mean[bcol+3];
        xv  = *(const float4*)&X[brow_base];
        gxv = *(const float4*)&gx[brow_base];
    }
    mv = *(const float4*)&M[brow_base];

    const size_t ghA_base = ((size_t)(b0 + (lane & 15)) * Tn) * Hn + w * 32 + ((lane >> 4) << 3);
    uint4 gha = *(const uint4*)&gh[ghA_base];
    unsigned short ghcd[2][4];
    #pragma unroll
    for (int nt = 0; nt < 2; ++nt)
        #pragma unroll
        for (int q = 0; q < 4; ++q)
            ghcd[nt][q] = gh[((size_t)(b0 + rowb + q) * Tn) * Hn + w * 32 + nt * 16 + c15];

    float h_cd[2][4] = {{0.f,0.f,0.f,0.f},{0.f,0.f,0.f,0.f}};
    float hd_cd[2][4], zz[2][4];
    const f4_t z4 = {0.f, 0.f, 0.f, 0.f};
    __syncthreads();   // staging visible

    for (int t = 0; t < Tn; ++t) {
        const int tn = (t + 1 < Tn) ? (t + 1) : (Tn - 1);

        // pin resident frags (named SSA values — remat becomes illegal)
        KV(whz0_0); KV(whz0_1); KV(whz0_2); KV(whz0_3);
        KV(whz0_4); KV(whz0_5); KV(whz0_6); KV(whz0_7);
        KV(whz1_0); KV(whz1_1); KV(whz1_2); KV(whz1_3);
        KV(whz1_4); KV(whz1_5); KV(whz1_6); KV(whz1_7);
        KV(whh0_0); KV(whh0_1); KV(whh0_2); KV(whh0_3);
        KV(whh0_4); KV(whh0_5); KV(whh0_6); KV(whh0_7);
        KV(whh1_0); KV(whh1_1); KV(whh1_2); KV(whh1_3);
        KV(whh1_4); KV(whh1_5); KV(whh1_6); KV(whh1_7);

        // ===== PH1: A-frag builds + t+1 prefetch =====
        {
            uint4 hA = *(const uint4*)&sh_hb[lane & 15][w * 32 + ((lane >> 4) << 3)];
            unsigned int ga[4] = {gha.x, gha.y, gha.z, gha.w};
            unsigned int ha[4] = {hA.x, hA.y, hA.z, hA.w};
            bf8_t hv;
            #pragma unroll
            for (int i = 0; i < 8; ++i) {
                float gf = bf2f((unsigned short)((ga[i >> 1] >> ((i & 1) * 16)) & 0xffffu));
                float hf = bf2f((unsigned short)((ha[i >> 1] >> ((i & 1) * 16)) & 0xffffu));
                hv[i] = (short)f2bf(gf * hf);
            }
            *(bf8_t*)&sA_hd[(w * 64 + lane) * 8] = hv;
        }
        #pragma unroll
        for (int nt = 0; nt < 2; ++nt)
            #pragma unroll
            for (int q = 0; q < 4; ++q)
                hd_cd[nt][q] = bf2f(ghcd[nt][q]) * h_cd[nt][q];

        if (lane < 32) {
            float mm[4] = {mv.x, mv.y, mv.z, mv.w};
            float xx[4] = {xv.x, xv.y, xv.z, xv.w};
            float gg[4] = {gxv.x, gxv.y, gxv.z, gxv.w};
            float xh[4];
            #pragma unroll
            for (int j = 0; j < 4; ++j) {
                xh[j] = mm[j] * xx[j] + (1.f - mm[j]) * (gg[j] * xp[j] + (1.f - gg[j]) * xb[j]);
                xp[j] = mm[j] * xx[j] + (1.f - mm[j]) * xp[j];
            }
            uint2 dd;
            dd.x = (unsigned int)f2bf(xh[0]) | ((unsigned int)f2bf(xh[1]) << 16);
            dd.y = (unsigned int)f2bf(xh[2]) | ((unsigned int)f2bf(xh[3]) << 16);
            *(uint2*)&sA_xh[(kt2 * 64 + fl) * 8 + half * 4] = dd;
        } else {
            uint2 dd;
            dd.x = (unsigned int)f2bf(mv.x) | ((unsigned int)f2bf(mv.y) << 16);
            dd.y = (unsigned int)f2bf(mv.z) | ((unsigned int)f2bf(mv.w) << 16);
            *(uint2*)&sA_m[(kt2 * 64 + fl) * 8 + half * 4] = dd;
        }
        {   // t+1 prefetch — rides across the lgkmcnt-only barriers
            const size_t ba = brow_base + (size_t)tn * Dn;
            mv = *(const float4*)&M[ba];
            if (lane < 32) {
                xv  = *(const float4*)&X[ba];
                gxv = *(const float4*)&gx[ba];
            }
            gha = *(const uint4*)&gh[ghA_base + (size_t)tn * Hn];
            #pragma unroll
            for (int nt = 0; nt < 2; ++nt)
                #pragma unroll
                for (int q = 0; q < 4; ++q)
                    ghcd[nt][q] = gh[((size_t)(b0 + rowb + q) * Tn + tn) * Hn + w * 32 + nt * 16 + c15];
        }
        lds_sync();   // bar0

        // ===== PH2: z and r gates (chains: regs + LDS only) =====
        bf8_t wxz[2][2], wxr[2][2], wmz[2][2], wmr[2][2];
        #pragma unroll
        for (int nt = 0; nt < 2; ++nt)
            #pragma unroll
            for (int kt = 0; kt < 2; ++kt) {
                wxz[nt][kt] = LD8(BA(pk + OFF_WX,         2 * w + nt, 2, kt, lane));
                wxr[nt][kt] = LD8(BA(pk + OFF_WX + 16384, 2 * w + nt, 2, kt, lane));
                wmz[nt][kt] = LD8(BA(pk + OFF_WM,         2 * w + nt, 2, kt, lane));
                wmr[nt][kt] = LD8(BA(pk + OFF_WM + 16384, 2 * w + nt, 2, kt, lane));
            }
        bf8_t xf0 = LD8(&sA_xh[lane * 8]), xf1 = LD8(&sA_xh[(64 + lane) * 8]);
        bf8_t mf0 = LD8(&sA_m [lane * 8]), mf1 = LD8(&sA_m [(64 + lane) * 8]);

        f4_t aZ0 = z4, aZ1 = z4, aR0 = z4, aR1 = z4;
#define ZR(KT) { \
        bf8_t hf  = LD8(&sA_hd[((KT) * 64 + lane) * 8]); \
        bf8_t wr0 = LD8(&sWh1[((2*w+0)*8 + (KT)) * 512 + lane * 8]); \
        bf8_t wr1 = LD8(&sWh1[((2*w+1)*8 + (KT)) * 512 + lane * 8]); \
        aZ0 = MF(hf, whz0_##KT, aZ0); aZ1 = MF(hf, whz1_##KT, aZ1); \
        aR0 = MF(hf, wr0, aR0);       aR1 = MF(hf, wr1, aR1); }
        ZR(0) ZR(1) ZR(2) ZR(3) ZR(4) ZR(5) ZR(6) ZR(7)
#undef ZR
        aZ0 = MF(xf0, wxz[0][0], aZ0); aZ0 = MF(xf1, wxz[0][1], aZ0);
        aZ0 = MF(mf0, wmz[0][0], aZ0); aZ0 = MF(mf1, wmz[0][1], aZ0);
        aZ1 = MF(xf0, wxz[1][0], aZ1); aZ1 = MF(xf1, wxz[1][1], aZ1);
        aZ1 = MF(mf0, wmz[1][0], aZ1); aZ1 = MF(mf1, wmz[1][1], aZ1);
        aR0 = MF(xf0, wxr[0][0], aR0); aR0 = MF(xf1, wxr[0][1], aR0);
        aR0 = MF(mf0, wmr[0][0], aR0); aR0 = MF(mf1, wmr[0][1], aR0);
        aR1 = MF(xf0, wxr[1][0], aR1); aR1 = MF(xf1, wxr[1][1], aR1);
        aR1 = MF(mf0, wmr[1][0], aR1); aR1 = MF(mf1, wmr[1][1], aR1);

        // issue PH3's streamed x-side weights now (a chain of lead)
        bf8_t wxh[2][2], wmh[2][2];
        #pragma unroll
        for (int nt = 0; nt < 2; ++nt)
            #pragma unroll
            for (int kt = 0; kt < 2; ++kt) {
                wxh[nt][kt] = LD8(BA(pk + OFF_WX + 32768, 2 * w + nt, 2, kt, lane));
                wmh[nt][kt] = LD8(BA(pk + OFF_WM + 32768, 2 * w + nt, 2, kt, lane));
            }
        #pragma unroll
        for (int nt = 0; nt < 2; ++nt) {
            const f4_t aZ = nt ? aZ1 : aZ0;
            const f4_t aR = nt ? aR1 : aR0;
            const int col = w * 32 + nt * 16 + c15;
            #pragma unroll
            for (int q = 0; q < 4; ++q) {
                const int r = rowb + q;
                float z  = 1.f / (1.f + __expf(-(aZ[q] + bz[nt])));
                float rr = 1.f / (1.f + __expf(-(aR[q] + brr[nt])));
                zz[nt][q] = z;
                sA_rhd[(w * 64 + ((col & 31) >> 3) * 16 + r) * 8 + (col & 7)] =
                    (short)f2bf(rr * hd_cd[nt][q]);
            }
        }
        lds_sync();   // bar1

        // ===== PH3: h_tilde + h update =====
        f4_t aH0 = z4, aH1 = z4;
#define HS(KT) { \
        bf8_t rf = LD8(&sA_rhd[((KT) * 64 + lane) * 8]); \
        aH0 = MF(rf, whh0_##KT, aH0); aH1 = MF(rf, whh1_##KT, aH1); }
        HS(0) HS(1) HS(2) HS(3) HS(4) HS(5) HS(6) HS(7)
#undef HS
        aH0 = MF(xf0, wxh[0][0], aH0); aH0 = MF(xf1, wxh[0][1], aH0);
        aH0 = MF(mf0, wmh[0][0], aH0); aH0 = MF(mf1, wmh[0][1], aH0);
        aH1 = MF(xf0, wxh[1][0], aH1); aH1 = MF(xf1, wxh[1][1], aH1);
        aH1 = MF(mf0, wmh[1][0], aH1); aH1 = MF(mf1, wmh[1][1], aH1);

        #pragma unroll
        for (int nt = 0; nt < 2; ++nt) {
            const f4_t aH = nt ? aH1 : aH0;
            const int col = w * 32 + nt * 16 + c15;
            #pragma unroll
            for (int q = 0; q < 4; ++q) {
                const int r = rowb + q;
                float pre = aH[q] + bh[nt];
                float a = fabsf(pre), e = __expf(-2.f * a);
                float th = copysignf((1.f - e) / (1.f + e), pre);
                float hn = (1.f - zz[nt][q]) * hd_cd[nt][q] + zz[nt][q] * th;
                h_cd[nt][q] = hn;
                sh_hb[r][col] = f2bf(hn);
            }
        }
        lds_sync();   // bar2
    }

    // ---- classifier ----
    #pragma unroll
    for (int rr2 = 0; rr2 < 2; ++rr2) {
        const int row = w * 2 + rr2;
        ushort4 hb = *(const ushort4*)&sh_hb[row][lane * 4];
        float4 wv  = *(const float4*)&W_cls[lane * 4];
        float p = bf2f(hb.x) * wv.x + bf2f(hb.y) * wv.y +
                  bf2f(hb.z) * wv.z + bf2f(hb.w) * wv.w;
        #pragma unroll
        for (int o = 32; o > 0; o >>= 1) p += __shfl_down(p, o, 64);
        if (lane == 0) out[b0 + row] = p + b_cls[0];
    }
}

// ---------------------------------------------------------------------------
// Fallback (R2 kernel) if ws_size < WS_NEED — not expected.
// ---------------------------------------------------------------------------
__global__ __launch_bounds__(512, 2) void grud_main(
    const float* __restrict__ X, const float* __restrict__ M, const float* __restrict__ Dl,
    const float* __restrict__ x_mean, const float* __restrict__ b_gx,
    const float* __restrict__ b_gh, const float* __restrict__ b_g,
    const float* __restrict__ W_cls, const float* __restrict__ b_cls,
    const short* __restrict__ pk, float* __restrict__ out)
{
    __shared__ float sh_h [BB][Hn];
    __shared__ float sh_xp[BB][Dn];
    __shared__ float sh_x [BB][Dn];
    __shared__ float sh_m [BB][Dn];
    __shared__ short sA_d  [2 * 64 * 8];
    __shared__ short sA_m  [2 * 64 * 8];
    __shared__ short sA_xh [2 * 64 * 8];
    __shared__ short sA_hd [8 * 64 * 8];
    __shared__ short sA_rhd[8 * 64 * 8];
    __shared__ float sh_bgx[Dn], sh_xmean[Dn], sh_bgh[Hn], sh_bg[3][Hn];

    const int tid  = threadIdx.x;
    const int w    = tid >> 6, lane = tid & 63;
    const int b0   = blockIdx.x * BB;
    const int rowb = (lane >> 4) * 4;
    const int c15  = lane & 15;

    for (int i = tid; i < BB * Hn; i += 512) (&sh_h[0][0])[i]  = 0.f;
    for (int i = tid; i < BB * Dn; i += 512) (&sh_xp[0][0])[i] = 0.f;
    if (tid < Dn) { sh_bgx[tid] = b_gx[tid]; sh_xmean[tid] = x_mean[tid]; }
    if (tid < Hn) sh_bgh[tid] = b_gh[tid];
    for (int i = tid; i < 3 * Hn; i += 512) (&sh_bg[0][0])[i] = b_g[i];
    __syncthreads();

    const short* whp  = pk + OFF_WH;
    const short* wxp  = pk + OFF_WX;
    const short* wmp  = pk + OFF_WM;
    const short* wghp = pk + OFF_WGH;
    const short* wgxp = pk + OFF_WGX;

    for (int t = 0; t < Tn; ++t) {
        if (tid < 128) {
            const int kt2 = tid >> 6, lf = tid & 63;
            const int r = lf & 15, db = kt2 * 32 + ((lf >> 4) << 3);
            const float* p = Dl + ((size_t)(b0 + r) * Tn + t) * Dn + db;
            float4 a = *(const float4*)p, b = *(const float4*)(p + 4);
            bf8_t v;
            v[0]=(short)f2bf(a.x); v[1]=(short)f2bf(a.y); v[2]=(short)f2bf(a.z); v[3]=(short)f2bf(a.w);
            v[4]=(short)f2bf(b.x); v[5]=(short)f2bf(b.y); v[6]=(short)f2bf(b.z); v[7]=(short)f2bf(b.w);
            *(bf8_t*)&sA_d[tid * 8] = v;
        } else if (tid < 256) {
            const int s2 = tid - 128;
            const int kt2 = s2 >> 6, lf = s2 & 63;
            const int r = lf & 15, db = kt2 * 32 + ((lf >> 4) << 3);
            const float* p = M + ((size_t)(b0 + r) * Tn + t) * Dn + db;
            float4 a = *(const float4*)p, b = *(const float4*)(p + 4);
            bf8_t v;
            v[0]=(short)f2bf(a.x); v[1]=(short)f2bf(a.y); v[2]=(short)f2bf(a.z); v[3]=(short)f2bf(a.w);
            v[4]=(short)f2bf(b.x); v[5]=(short)f2bf(b.y); v[6]=(short)f2bf(b.z); v[7]=(short)f2bf(b.w);
            *(bf8_t*)&sA_m[s2 * 8] = v;
        } else {
            const int s2 = tid - 256, r = s2 >> 4, seg = (s2 & 15) * 4;
            const size_t off = ((size_t)(b0 + r) * Tn + t) * Dn + seg;
            *(float4*)&sh_x[r][seg] = *(const float4*)(X + off);
            *(float4*)&sh_m[r][seg] = *(const float4*)(M + off);
        }
        __syncthreads();

        bf8_t df0 = *(const bf8_t*)&sA_d[(0 * 64 + lane) * 8];
        bf8_t df1 = *(const bf8_t*)&sA_d[(1 * 64 + lane) * 8];
        f4_t accG0 = {0.f,0.f,0.f,0.f}, accG1 = {0.f,0.f,0.f,0.f};
        accG0 = MFp(df0, BA(wghp, 2*w+0, 2, 0, lane), accG0);
        accG0 = MFp(df1, BA(wghp, 2*w+0, 2, 1, lane), accG0);
        accG1 = MFp(df0, BA(wghp, 2*w+1, 2, 0, lane), accG1);
        accG1 = MFp(df1, BA(wghp, 2*w+1, 2, 1, lane), accG1);
        if (w < 4) {
            f4_t aGx = {0.f,0.f,0.f,0.f};
            aGx = MFp(df0, BA(wgxp, w, 2, 0, lane), aGx);
            aGx = MFp(df1, BA(wgxp, w, 2, 1, lane), aGx);
            const int col = w * 16 + c15;
            #pragma unroll
            for (int q = 0; q < 4; ++q) {
                const int r = rowb + q;
                float gxs = __expf(-fmaxf(aGx[q] + sh_bgx[col], 0.f));
                float mvs = sh_m[r][col], xvs = sh_x[r][col], xpv = sh_xp[r][col];
                float xh  = mvs * xvs + (1.f - mvs) * (gxs * xpv + (1.f - gxs) * sh_xmean[col]);
                sh_xp[r][col] = mvs * xvs + (1.f - mvs) * xpv;
                sA_xh[((col >> 5) * 64 + (((col & 31) >> 3) << 4) + r) * 8 + (col & 7)]
                    = (short)f2bf(xh);
            }
        }
        __syncthreads();

        bf8_t xf0 = *(const bf8_t*)&sA_xh[(0 * 64 + lane) * 8];
        bf8_t xf1 = *(const bf8_t*)&sA_xh[(1 * 64 + lane) * 8];
        bf8_t mf0 = *(const bf8_t*)&sA_m [(0 * 64 + lane) * 8];
        bf8_t mf1 = *(const bf8_t*)&sA_m [(1 * 64 + lane) * 8];
        f4_t accP[3][2];
        #pragma unroll
        for (int g = 0; g < 3; ++g) {
            const short* bx = wxp + (size_t)g * 16384;
            const short* bm = wmp + (size_t)g * 16384;
            #pragma unroll
            for (int nt = 0; nt < 2; ++nt) {
                const int ntG = 2 * w + nt;
                f4_t a = {0.f,0.f,0.f,0.f};
                a = MFp(xf0, BA(bx, ntG, 2, 0, lane), a);
                a = MFp(xf1, BA(bx, ntG, 2, 1, lane), a);
                a = MFp(mf0, BA(bm, ntG, 2, 0, lane), a);
                a = MFp(mf1, BA(bm, ntG, 2, 1, lane), a);
                accP[g][nt] = a;
            }
        }
        float hd2[2][4];
        #pragma unroll
        for (int nt = 0; nt < 2; ++nt) {
            const f4_t aG = nt ? accG1 : accG0;
            const int col = w * 32 + nt * 16 + c15;
            #pragma unroll
            for (int q = 0; q < 4; ++q) {
                const int r = rowb + q;
                float gh2 = __expf(-fmaxf(aG[q] + sh_bgh[col], 0.f));
                float hdv = gh2 * sh_h[r][col];
                hd2[nt][q] = hdv;
                sA_hd[((size_t)w * 64 + (((col & 31) >> 3) << 4) + r) * 8 + (col & 7)]
                    = (short)f2bf(hdv);
            }
        }
        __syncthreads();

        f4_t accZ[2] = {accP[0][0], accP[0][1]};
        f4_t accR[2] = {accP[1][0], accP[1][1]};
        #pragma unroll
        for (int kt = 0; kt < 8; ++kt) {
            bf8_t hf = *(const bf8_t*)&sA_hd[(kt * 64 + lane) * 8];
            #pragma unroll
            for (int nt = 0; nt < 2; ++nt) {
                const int ntG = 2 * w + nt;
                accZ[nt] = MFp(hf, BA(whp + 0 * 65536, ntG, 8, kt, lane), accZ[nt]);
                accR[nt] = MFp(hf, BA(whp + 1 * 65536, ntG, 8, kt, lane), accR[nt]);
            }
        }
        float zz2[2][4];
        #pragma unroll
        for (int nt = 0; nt < 2; ++nt) {
            const int col = w * 32 + nt * 16 + c15;
            #pragma unroll
            for (int q = 0; q < 4; ++q) {
                const int r = rowb + q;
                float z  = 1.f / (1.f + __expf(-(accZ[nt][q] + sh_bg[0][col])));
                float rv = 1.f / (1.f + __expf(-(accR[nt][q] + sh_bg[1][col])));
                zz2[nt][q] = z;
                sA_rhd[((size_t)w * 64 + (((col & 31) >> 3) << 4) + r) * 8 + (col & 7)]
                    = (short)f2bf(rv * hd2[nt][q]);
            }
        }
        __syncthreads();

        f4_t accH[2] = {accP[2][0], accP[2][1]};
        #pragma unroll
        for (int kt = 0; kt < 8; ++kt) {
            bf8_t hf = *(const bf8_t*)&sA_rhd[(kt * 64 + lane) * 8];
            #pragma unroll
            for (int nt = 0; nt < 2; ++nt)
                accH[nt] = MFp(hf, BA(whp + 2 * 65536, 2 * w + nt, 8, kt, lane), accH[nt]);
        }
        #pragma unroll
        for (int nt = 0; nt < 2; ++nt) {
            const int col = w * 32 + nt * 16 + c15;
            #pragma unroll
            for (int q = 0; q < 4; ++q) {
                const int r = rowb + q;
                float pre = accH[nt][q] + sh_bg[2][col];
                float a = fabsf(pre), e = __expf(-2.f * a);
                float th = copysignf((1.f - e) / (1.f + e), pre);
                sh_h[r][col] = (1.f - zz2[nt][q]) * hd2[nt][q] + zz2[nt][q] * th;
            }
        }
        __syncthreads();
    }

    if (tid < BB) {
        float s2 = 0.f;
        for (int k = 0; k < Hn; ++k) s2 = fmaf(sh_h[tid][k], W_cls[k], s2);
        out[b0 + tid] = s2 + b_cls[0];
    }
}

extern "C" void kernel_launch(void* const* d_in, const int* in_sizes, int n_in,
                              void* d_out, int out_size, void* d_ws, size_t ws_size,
                              hipStream_t stream) {
    const float* X      = (const float*)d_in[0];
    const float* M      = (const float*)d_in[1];
    const float* Dl     = (const float*)d_in[2];
    const float* x_mean = (const float*)d_in[3];
    const float* W_gx   = (const float*)d_in[4];
    const float* b_gx   = (const float*)d_in[5];
    const float* W_gh   = (const float*)d_in[6];
    const float* b_gh   = (const float*)d_in[7];
    const float* W_x    = (const float*)d_in[8];
    const float* W_h    = (const float*)d_in[9];
    const float* W_m    = (const float*)d_in[10];
    const float* b_g    = (const float*)d_in[11];
    const float* W_cls  = (const float*)d_in[12];
    const float* b_cls  = (const float*)d_in[13];
    float* out = (float*)d_out;
    short* pk  = (short*)d_ws;

    hipLaunchKernelGGL(pack_weights, dim3((PACK_SLOTS + 255) / 256), dim3(256), 0, stream,
                       W_gx, W_gh, W_x, W_h, W_m, pk);

    if (ws_size >= WS_NEED) {
        float*          gxbuf = (float*)((char*)d_ws + GX_OFF);
        unsigned short* ghbuf = (unsigned short*)((char*)d_ws + GH_OFF);
        hipLaunchKernelGGL(grud_prepass, dim3(NBLK * Tn), dim3(256), 0, stream,
                           Dl, b_gx, b_gh, pk, gxbuf, ghbuf);
        hipLaunchKernelGGL(grud_rec9, dim3(NBLK), dim3(512), 0, stream,
                           X, M, x_mean, b_g, W_cls, b_cls, pk, gxbuf, ghbuf, out);
    } else {
        hipLaunchKernelGGL(grud_main, dim3(NBLK), dim3(512), 0, stream,
                           X, M, Dl, x_mean, b_gx, b_gh, b_g, W_cls, b_cls, pk, out);
    }
}

// Round 12
// 2611.261 us; speedup vs baseline: 1.6425x; 1.6425x over previous
//
#include <hip/hip_runtime.h>

// GRU-D, round 12.
// pack -> prepass (gamma_x f32, gamma_h bf16) -> grud_rec12.
// rec12 = rec8 restructured to 16 waves/block (1024 thr), 1 ntile/wave:
//   - 4 waves/SIMD (vs 2): doubled latency hiding on the 32 active CUs,
//   - per-wave step work halved (36 MFMA, 1-ntile epilogues),
//   - per-wave resident W_h[0]/W_h[2] = 64 VGPR -> may fit the 128 budget
//     naturally (no pins/attributes; builtins only — AGPR asm abandoned).
// Waves 0-7 keep rec8's builder roles (hd A-frags, xh/m frags, prefetches);
// waves 8-15 are compute-only for their ntiles. lgkmcnt-only barriers kept.

constexpr int Bn = 512, Tn = 256, Dn = 64, Hn = 256;
constexpr int BB = 16, NBLK = Bn / BB;   // 32 blocks

typedef __attribute__((ext_vector_type(8))) short bf8_t;
typedef __attribute__((ext_vector_type(4))) float f4_t;

constexpr size_t OFF_WH  = 0;
constexpr size_t OFF_WX  = 196608;
constexpr size_t OFF_WM  = 245760;
constexpr size_t OFF_WGH = 294912;
constexpr size_t OFF_WGX = 311296;
constexpr int    PACK_SLOTS = 39424;

constexpr size_t GX_OFF  = (size_t)1 << 20;
constexpr size_t GH_OFF  = GX_OFF + (size_t)Bn * Tn * Dn * 4;
constexpr size_t WS_NEED = GH_OFF + (size_t)Bn * Tn * Hn * 2;    // 101,711,872

__device__ __forceinline__ unsigned short f2bf(float x) {
    union { float f; unsigned int u; } v; v.f = x;
    unsigned int r = (v.u + 0x7fffu + ((v.u >> 16) & 1u)) >> 16;   // RNE
    return (unsigned short)r;
}
__device__ __forceinline__ float bf2f(unsigned short u) {
    union { unsigned int i; float f; } v; v.i = ((unsigned int)u) << 16; return v.f;
}
__device__ __forceinline__ bf8_t LD8(const short* p) { return *(const bf8_t*)p; }
__device__ __forceinline__ f4_t MF(bf8_t a, bf8_t b, f4_t c) {
    return __builtin_amdgcn_mfma_f32_16x16x32_bf16(a, b, c, 0, 0, 0);
}
__device__ __forceinline__ f4_t MFp(bf8_t a, const short* bp, f4_t c) {
    return MF(a, LD8(bp), c);
}
__device__ __forceinline__ const short* BA(const short* p, int ntG, int KT, int kt, int lane) {
    return p + (((size_t)ntG * KT + kt) * 64 + lane) * 8;
}
// LDS-only barrier: drains LDS ops, leaves global (vmcnt) loads in flight.
__device__ __forceinline__ void lds_sync() {
    __builtin_amdgcn_sched_barrier(0);
    asm volatile("s_waitcnt lgkmcnt(0)" ::: "memory");
    __builtin_amdgcn_s_barrier();
    __builtin_amdgcn_sched_barrier(0);
}

// ---------------------------------------------------------------------------
// pack_weights (unchanged, proven)
// ---------------------------------------------------------------------------
__global__ __launch_bounds__(256) void pack_weights(
    const float* __restrict__ W_gx, const float* __restrict__ W_gh,
    const float* __restrict__ W_x,  const float* __restrict__ W_h,
    const float* __restrict__ W_m,  short* __restrict__ out)
{
    const int slot = blockIdx.x * 256 + threadIdx.x;
    if (slot >= PACK_SLOTS) return;

    const float* w; int ldn, l, kt, j, kbase;
    if (slot < 24576) {
        int g = slot >> 13, rem = slot & 8191;
        int ntG = rem >> 9, r2 = rem & 511;
        kt = r2 >> 6; l = r2 & 63;
        j = ntG * 16 + (l & 15);
        w = W_h + (size_t)g * Hn * Hn; ldn = Hn;
    } else if (slot < 30720) {
        int s = slot - 24576;
        int g = s >> 11, rem = s & 2047;
        int ntG = rem >> 7, r2 = rem & 127;
        kt = r2 >> 6; l = r2 & 63;
        j = ntG * 16 + (l & 15);
        w = W_x + (size_t)g * Dn * Hn; ldn = Hn;
    } else if (slot < 36864) {
        int s = slot - 30720;
        int g = s >> 11, rem = s & 2047;
        int ntG = rem >> 7, r2 = rem & 127;
        kt = r2 >> 6; l = r2 & 63;
        j = ntG * 16 + (l & 15);
        w = W_m + (size_t)g * Dn * Hn; ldn = Hn;
    } else if (slot < 38912) {
        int s = slot - 36864;
        int ntG = s >> 7, r2 = s & 127;
        kt = r2 >> 6; l = r2 & 63;
        j = ntG * 16 + (l & 15);
        w = W_gh; ldn = Hn;
    } else {
        int s = slot - 38912;
        int ntG = s >> 7, r2 = s & 127;
        kt = r2 >> 6; l = r2 & 63;
        j = ntG * 16 + (l & 15);
        w = W_gx; ldn = Dn;
    }
    kbase = kt * 32 + ((l >> 4) << 3);
    bf8_t v;
    #pragma unroll
    for (int i = 0; i < 8; ++i)
        v[i] = (short)f2bf(w[(size_t)(kbase + i) * ldn + j]);
    *(bf8_t*)&out[(size_t)slot * 8] = v;
}

// ---------------------------------------------------------------------------
// prepass (unchanged, proven)
// ---------------------------------------------------------------------------
__global__ __launch_bounds__(256) void grud_prepass(
    const float* __restrict__ Dl, const float* __restrict__ b_gx,
    const float* __restrict__ b_gh, const short* __restrict__ pk,
    float* __restrict__ gx, unsigned short* __restrict__ gh)
{
    __shared__ short sDf[2 * 64 * 8];
    const int tid = threadIdx.x, w = tid >> 6, lane = tid & 63;
    const int bt = blockIdx.x >> 8, t = blockIdx.x & 255;
    const int b0 = bt * 16;
    const int c15 = lane & 15, rowb = (lane >> 4) * 4;

    if (w < 2) {
        const int row = lane & 15, cb = w * 32 + ((lane >> 4) << 3);
        const float* p = Dl + ((size_t)(b0 + row) * Tn + t) * Dn + cb;
        float4 a = *(const float4*)p, b = *(const float4*)(p + 4);
        bf8_t v;
        v[0]=(short)f2bf(a.x); v[1]=(short)f2bf(a.y); v[2]=(short)f2bf(a.z); v[3]=(short)f2bf(a.w);
        v[4]=(short)f2bf(b.x); v[5]=(short)f2bf(b.y); v[6]=(short)f2bf(b.z); v[7]=(short)f2bf(b.w);
        *(bf8_t*)&sDf[(w * 64 + lane) * 8] = v;
    }
    __syncthreads();
    bf8_t df0 = *(const bf8_t*)&sDf[lane * 8];
    bf8_t df1 = *(const bf8_t*)&sDf[(64 + lane) * 8];

    #pragma unroll
    for (int i = 0; i < 4; ++i) {
        const int ntG = 4 * w + i;
        f4_t acc = {0.f, 0.f, 0.f, 0.f};
        acc = MFp(df0, BA(pk + OFF_WGH, ntG, 2, 0, lane), acc);
        acc = MFp(df1, BA(pk + OFF_WGH, ntG, 2, 1, lane), acc);
        const int col = ntG * 16 + c15;
        const float bb = b_gh[col];
        #pragma unroll
        for (int q = 0; q < 4; ++q) {
            const int r = rowb + q;
            gh[((size_t)(b0 + r) * Tn + t) * Hn + col] =
                f2bf(__expf(-fmaxf(acc[q] + bb, 0.f)));
        }
    }
    {
        f4_t acc = {0.f, 0.f, 0.f, 0.f};
        acc = MFp(df0, BA(pk + OFF_WGX, w, 2, 0, lane), acc);
        acc = MFp(df1, BA(pk + OFF_WGX, w, 2, 1, lane), acc);
        const int col = w * 16 + c15;
        const float bb = b_gx[col];
        #pragma unroll
        for (int q = 0; q < 4; ++q) {
            const int r = rowb + q;
            gx[((size_t)(b0 + r) * Tn + t) * Dn + col] =
                __expf(-fmaxf(acc[q] + bb, 0.f));
        }
    }
}

// ---------------------------------------------------------------------------
// grud_rec12: 16 waves/block, 1 ntile/wave.
// ---------------------------------------------------------------------------
__global__ __launch_bounds__(1024, 4) void grud_rec12(
    const float* __restrict__ X, const float* __restrict__ M,
    const float* __restrict__ x_mean, const float* __restrict__ b_g,
    const float* __restrict__ W_cls, const float* __restrict__ b_cls,
    const short* __restrict__ pk, const float* __restrict__ gx,
    const unsigned short* __restrict__ gh, float* __restrict__ out)
{
    __shared__ short sWh1[16 * 8 * 64 * 8];      // 131072 B : W_h[1] B-frags
    __shared__ unsigned short sh_hb[16][264];    //   8448 B : h state (bf16)
    __shared__ short sA_xh[2 * 64 * 8];
    __shared__ short sA_m [2 * 64 * 8];
    __shared__ short sA_hd[8 * 64 * 8];
    __shared__ short sA_rhd[8 * 64 * 8];         // => 160000 B

    const int tid = threadIdx.x, w = tid >> 6, lane = tid & 63;
    const int c15 = lane & 15, rowb = (lane >> 4) * 4;
    const int b0 = blockIdx.x * BB;
    const int col = w * 16 + c15;                // this wave's output column

    // per-wave resident candidates: 8+8 frags = 64 VGPR (allocator decides)
    bf8_t whz[8], whh[8];
    #pragma unroll
    for (int kt = 0; kt < 8; ++kt) {
        whz[kt] = LD8(BA(pk + OFF_WH,             w, 8, kt, lane));
        whh[kt] = LD8(BA(pk + OFF_WH + 2 * 65536, w, 8, kt, lane));
    }
    for (int c = tid; c < 8192; c += 1024)
        *(uint4*)&sWh1[c * 8] = *(const uint4*)&pk[OFF_WH + 65536 + (size_t)c * 8];
    for (int i = tid; i < 16 * 264; i += 1024) (&sh_hb[0][0])[i] = 0;

    const float bz  = b_g[0 * Hn + col];
    const float brr = b_g[1 * Hn + col];
    const float bh  = b_g[2 * Hn + col];

    // builder mapping (waves 0-7 only), rec8-proven
    const int s    = (w & 7) * 32 + (lane & 31);
    const int kt2  = s >> 7, fl = (s >> 1) & 63, half = s & 1;
    const int brow = fl & 15, bcol = kt2 * 32 + ((fl >> 4) << 3) + half * 4;
    const size_t brow_base = ((size_t)(b0 + brow) * Tn) * Dn + bcol;

    float xb[4] = {0.f, 0.f, 0.f, 0.f};
    float xp[4] = {0.f, 0.f, 0.f, 0.f};
    float4 mv = {0,0,0,0}, xv = {0,0,0,0}, gxv = {0,0,0,0};
    if (w < 8) {
        if (lane < 32) {
            xb[0]=x_mean[bcol]; xb[1]=x_mean[bcol+1]; xb[2]=x_mean[bcol+2]; xb[3]=x_mean[bcol+3];
            xv  = *(const float4*)&X[brow_base];
            gxv = *(const float4*)&gx[brow_base];
        }
        mv = *(const float4*)&M[brow_base];
    }

    // gamma_h prefetch: A-layout (waves 0-7, ktile w), C/D layout (all waves)
    const size_t ghA_base = ((size_t)(b0 + (lane & 15)) * Tn) * Hn
                          + (w & 7) * 32 + ((lane >> 4) << 3);
    uint4 gha = {0,0,0,0};
    if (w < 8) gha = *(const uint4*)&gh[ghA_base];
    unsigned short ghcd[4];
    #pragma unroll
    for (int q = 0; q < 4; ++q)
        ghcd[q] = gh[((size_t)(b0 + rowb + q) * Tn) * Hn + col];

    float h_cd[4] = {0.f, 0.f, 0.f, 0.f};
    float hd_cd[4], zz[4];
    const f4_t z4 = {0.f, 0.f, 0.f, 0.f};
    __syncthreads();

    for (int t = 0; t < Tn; ++t) {
        const int tn = (t + 1 < Tn) ? (t + 1) : (Tn - 1);

        // ===== PH1: A-frag builds (waves 0-7) + t+1 prefetch =====
        if (w < 8) {
            uint4 hA = *(const uint4*)&sh_hb[lane & 15][(w & 7) * 32 + ((lane >> 4) << 3)];
            unsigned int ga[4] = {gha.x, gha.y, gha.z, gha.w};
            unsigned int ha[4] = {hA.x, hA.y, hA.z, hA.w};
            bf8_t hv;
            #pragma unroll
            for (int i = 0; i < 8; ++i) {
                float gf = bf2f((unsigned short)((ga[i >> 1] >> ((i & 1) * 16)) & 0xffffu));
                float hf = bf2f((unsigned short)((ha[i >> 1] >> ((i & 1) * 16)) & 0xffffu));
                hv[i] = (short)f2bf(gf * hf);
            }
            *(bf8_t*)&sA_hd[(w * 64 + lane) * 8] = hv;

            if (lane < 32) {
                float mm[4] = {mv.x, mv.y, mv.z, mv.w};
                float xx[4] = {xv.x, xv.y, xv.z, xv.w};
                float gg[4] = {gxv.x, gxv.y, gxv.z, gxv.w};
                float xh[4];
                #pragma unroll
                for (int j = 0; j < 4; ++j) {
                    xh[j] = mm[j] * xx[j] + (1.f - mm[j]) * (gg[j] * xp[j] + (1.f - gg[j]) * xb[j]);
                    xp[j] = mm[j] * xx[j] + (1.f - mm[j]) * xp[j];
                }
                uint2 dd;
                dd.x = (unsigned int)f2bf(xh[0]) | ((unsigned int)f2bf(xh[1]) << 16);
                dd.y = (unsigned int)f2bf(xh[2]) | ((unsigned int)f2bf(xh[3]) << 16);
                *(uint2*)&sA_xh[(kt2 * 64 + fl) * 8 + half * 4] = dd;
            } else {
                uint2 dd;
                dd.x = (unsigned int)f2bf(mv.x) | ((unsigned int)f2bf(mv.y) << 16);
                dd.y = (unsigned int)f2bf(mv.z) | ((unsigned int)f2bf(mv.w) << 16);
                *(uint2*)&sA_m[(kt2 * 64 + fl) * 8 + half * 4] = dd;
            }
            // t+1 prefetch (builder streams)
            const size_t ba = brow_base + (size_t)tn * Dn;
            mv = *(const float4*)&M[ba];
            if (lane < 32) {
                xv  = *(const float4*)&X[ba];
                gxv = *(const float4*)&gx[ba];
            }
            gha = *(const uint4*)&gh[ghA_base + (size_t)tn * Hn];
        }
        // all waves: hd in C/D layout + t+1 ghcd prefetch
        #pragma unroll
        for (int q = 0; q < 4; ++q)
            hd_cd[q] = bf2f(ghcd[q]) * h_cd[q];
        #pragma unroll
        for (int q = 0; q < 4; ++q)
            ghcd[q] = gh[((size_t)(b0 + rowb + q) * Tn + tn) * Hn + col];
        lds_sync();   // bar0

        // ===== PH2: z and r gates (1 ntile) =====
        bf8_t wxz[2], wxr[2], wmz[2], wmr[2];
        #pragma unroll
        for (int kt = 0; kt < 2; ++kt) {
            wxz[kt] = LD8(BA(pk + OFF_WX,         w, 2, kt, lane));
            wxr[kt] = LD8(BA(pk + OFF_WX + 16384, w, 2, kt, lane));
            wmz[kt] = LD8(BA(pk + OFF_WM,         w, 2, kt, lane));
            wmr[kt] = LD8(BA(pk + OFF_WM + 16384, w, 2, kt, lane));
        }
        bf8_t xf0 = LD8(&sA_xh[lane * 8]), xf1 = LD8(&sA_xh[(64 + lane) * 8]);
        bf8_t mf0 = LD8(&sA_m [lane * 8]), mf1 = LD8(&sA_m [(64 + lane) * 8]);

        f4_t aZ = z4, aR = z4;
        #pragma unroll
        for (int kt = 0; kt < 8; ++kt) {
            bf8_t hf = LD8(&sA_hd[(kt * 64 + lane) * 8]);
            bf8_t wr = LD8(&sWh1[(w * 8 + kt) * 512 + lane * 8]);
            aZ = MF(hf, whz[kt], aZ);
            aR = MF(hf, wr, aR);
        }
        aZ = MF(xf0, wxz[0], aZ); aZ = MF(xf1, wxz[1], aZ);
        aZ = MF(mf0, wmz[0], aZ); aZ = MF(mf1, wmz[1], aZ);
        aR = MF(xf0, wxr[0], aR); aR = MF(xf1, wxr[1], aR);
        aR = MF(mf0, wmr[0], aR); aR = MF(mf1, wmr[1], aR);

        // issue PH3's streamed x-side weights now (a chain of lead)
        bf8_t wxh[2], wmh[2];
        #pragma unroll
        for (int kt = 0; kt < 2; ++kt) {
            wxh[kt] = LD8(BA(pk + OFF_WX + 32768, w, 2, kt, lane));
            wmh[kt] = LD8(BA(pk + OFF_WM + 32768, w, 2, kt, lane));
        }
        #pragma unroll
        for (int q = 0; q < 4; ++q) {
            const int r = rowb + q;
            float z  = 1.f / (1.f + __expf(-(aZ[q] + bz)));
            float rr = 1.f / (1.f + __expf(-(aR[q] + brr)));
            zz[q] = z;
            sA_rhd[((w >> 1) * 64 + ((col & 31) >> 3) * 16 + r) * 8 + (col & 7)] =
                (short)f2bf(rr * hd_cd[q]);
        }
        lds_sync();   // bar1

        // ===== PH3: h_tilde + h update =====
        f4_t aH = z4;
        #pragma unroll
        for (int kt = 0; kt < 8; ++kt) {
            bf8_t rf = LD8(&sA_rhd[(kt * 64 + lane) * 8]);
            aH = MF(rf, whh[kt], aH);
        }
        aH = MF(xf0, wxh[0], aH); aH = MF(xf1, wxh[1], aH);
        aH = MF(mf0, wmh[0], aH); aH = MF(mf1, wmh[1], aH);

        #pragma unroll
        for (int q = 0; q < 4; ++q) {
            const int r = rowb + q;
            float pre = aH[q] + bh;
            float a = fabsf(pre), e = __expf(-2.f * a);
            float th = copysignf((1.f - e) / (1.f + e), pre);
            float hn = (1.f - zz[q]) * hd_cd[q] + zz[q] * th;
            h_cd[q] = hn;
            sh_hb[r][col] = f2bf(hn);
        }
        lds_sync();   // bar2
    }

    // ---- classifier: wave w reduces row w ----
    {
        ushort4 hb = *(const ushort4*)&sh_hb[w][lane * 4];
        float4 wv  = *(const float4*)&W_cls[lane * 4];
        float p = bf2f(hb.x) * wv.x + bf2f(hb.y) * wv.y +
                  bf2f(hb.z) * wv.z + bf2f(hb.w) * wv.w;
        #pragma unroll
        for (int o = 32; o > 0; o >>= 1) p += __shfl_down(p, o, 64);
        if (lane == 0) out[b0 + w] = p + b_cls[0];
    }
}

// ---------------------------------------------------------------------------
// Fallback (R2 kernel) if ws_size < WS_NEED — not expected.
// ---------------------------------------------------------------------------
__global__ __launch_bounds__(512, 2) void grud_main(
    const float* __restrict__ X, const float* __restrict__ M, const float* __restrict__ Dl,
    const float* __restrict__ x_mean, const float* __restrict__ b_gx,
    const float* __restrict__ b_gh, const float* __restrict__ b_g,
    const float* __restrict__ W_cls, const float* __restrict__ b_cls,
    const short* __restrict__ pk, float* __restrict__ out)
{
    __shared__ float sh_h [BB][Hn];
    __shared__ float sh_xp[BB][Dn];
    __shared__ float sh_x [BB][Dn];
    __shared__ float sh_m [BB][Dn];
    __shared__ short sA_d  [2 * 64 * 8];
    __shared__ short sA_m  [2 * 64 * 8];
    __shared__ short sA_xh [2 * 64 * 8];
    __shared__ short sA_hd [8 * 64 * 8];
    __shared__ short sA_rhd[8 * 64 * 8];
    __shared__ float sh_bgx[Dn], sh_xmean[Dn], sh_bgh[Hn], sh_bg[3][Hn];

    const int tid  = threadIdx.x;
    const int w    = tid >> 6, lane = tid & 63;
    const int b0   = blockIdx.x * BB;
    const int rowb = (lane >> 4) * 4;
    const int c15  = lane & 15;

    for (int i = tid; i < BB * Hn; i += 512) (&sh_h[0][0])[i]  = 0.f;
    for (int i = tid; i < BB * Dn; i += 512) (&sh_xp[0][0])[i] = 0.f;
    if (tid < Dn) { sh_bgx[tid] = b_gx[tid]; sh_xmean[tid] = x_mean[tid]; }
    if (tid < Hn) sh_bgh[tid] = b_gh[tid];
    for (int i = tid; i < 3 * Hn; i += 512) (&sh_bg[0][0])[i] = b_g[i];
    __syncthreads();

    const short* whp  = pk + OFF_WH;
    const short* wxp  = pk + OFF_WX;
    const short* wmp  = pk + OFF_WM;
    const short* wghp = pk + OFF_WGH;
    const short* wgxp = pk + OFF_WGX;

    for (int t = 0; t < Tn; ++t) {
        if (tid < 128) {
            const int kt2 = tid >> 6, lf = tid & 63;
            const int r = lf & 15, db = kt2 * 32 + ((lf >> 4) << 3);
            const float* p = Dl + ((size_t)(b0 + r) * Tn + t) * Dn + db;
            float4 a = *(const float4*)p, b = *(const float4*)(p + 4);
            bf8_t v;
            v[0]=(short)f2bf(a.x); v[1]=(short)f2bf(a.y); v[2]=(short)f2bf(a.z); v[3]=(short)f2bf(a.w);
            v[4]=(short)f2bf(b.x); v[5]=(short)f2bf(b.y); v[6]=(short)f2bf(b.z); v[7]=(short)f2bf(b.w);
            *(bf8_t*)&sA_d[tid * 8] = v;
        } else if (tid < 256) {
            const int s2 = tid - 128;
            const int kt2 = s2 >> 6, lf = s2 & 63;
            const int r = lf & 15, db = kt2 * 32 + ((lf >> 4) << 3);
            const float* p = M + ((size_t)(b0 + r) * Tn + t) * Dn + db;
            float4 a = *(const float4*)p, b = *(const float4*)(p + 4);
            bf8_t v;
            v[0]=(short)f2bf(a.x); v[1]=(short)f2bf(a.y); v[2]=(short)f2bf(a.z); v[3]=(short)f2bf(a.w);
            v[4]=(short)f2bf(b.x); v[5]=(short)f2bf(b.y); v[6]=(short)f2bf(b.z); v[7]=(short)f2bf(b.w);
            *(bf8_t*)&sA_m[s2 * 8] = v;
        } else {
            const int s2 = tid - 256, r = s2 >> 4, seg = (s2 & 15) * 4;
            const size_t off = ((size_t)(b0 + r) * Tn + t) * Dn + seg;
            *(float4*)&sh_x[r][seg] = *(const float4*)(X + off);
            *(float4*)&sh_m[r][seg] = *(const float4*)(M + off);
        }
        __syncthreads();

        bf8_t df0 = *(const bf8_t*)&sA_d[(0 * 64 + lane) * 8];
        bf8_t df1 = *(const bf8_t*)&sA_d[(1 * 64 + lane) * 8];
        f4_t accG0 = {0.f,0.f,0.f,0.f}, accG1 = {0.f,0.f,0.f,0.f};
        accG0 = MFp(df0, BA(wghp, 2*w+0, 2, 0, lane), accG0);
        accG0 = MFp(df1, BA(wghp, 2*w+0, 2, 1, lane), accG0);
        accG1 = MFp(df0, BA(wghp, 2*w+1, 2, 0, lane), accG1);
        accG1 = MFp(df1, BA(wghp, 2*w+1, 2, 1, lane), accG1);
        if (w < 4) {
            f4_t aGx = {0.f,0.f,0.f,0.f};
            aGx = MFp(df0, BA(wgxp, w, 2, 0, lane), aGx);
            aGx = MFp(df1, BA(wgxp, w, 2, 1, lane), aGx);
            const int col = w * 16 + c15;
            #pragma unroll
            for (int q = 0; q < 4; ++q) {
                const int r = rowb + q;
                float gxs = __expf(-fmaxf(aGx[q] + sh_bgx[col], 0.f));
                float mvs = sh_m[r][col], xvs = sh_x[r][col], xpv = sh_xp[r][col];
                float xh  = mvs * xvs + (1.f - mvs) * (gxs * xpv + (1.f - gxs) * sh_xmean[col]);
                sh_xp[r][col] = mvs * xvs + (1.f - mvs) * xpv;
                sA_xh[((col >> 5) * 64 + (((col & 31) >> 3) << 4) + r) * 8 + (col & 7)]
                    = (short)f2bf(xh);
            }
        }
        __syncthreads();

        bf8_t xf0 = *(const bf8_t*)&sA_xh[(0 * 64 + lane) * 8];
        bf8_t xf1 = *(const bf8_t*)&sA_xh[(1 * 64 + lane) * 8];
        bf8_t mf0 = *(const bf8_t*)&sA_m [(0 * 64 + lane) * 8];
        bf8_t mf1 = *(const bf8_t*)&sA_m [(1 * 64 + lane) * 8];
        f4_t accP[3][2];
        #pragma unroll
        for (int g = 0; g < 3; ++g) {
            const short* bx = wxp + (size_t)g * 16384;
            const short* bm = wmp + (size_t)g * 16384;
            #pragma unroll
            for (int nt = 0; nt < 2; ++nt) {
                const int ntG = 2 * w + nt;
                f4_t a = {0.f,0.f,0.f,0.f};
                a = MFp(xf0, BA(bx, ntG, 2, 0, lane), a);
                a = MFp(xf1, BA(bx, ntG, 2, 1, lane), a);
                a = MFp(mf0, BA(bm, ntG, 2, 0, lane), a);
                a = MFp(mf1, BA(bm, ntG, 2, 1, lane), a);
                accP[g][nt] = a;
            }
        }
        float hd2[2][4];
        #pragma unroll
        for (int nt = 0; nt < 2; ++nt) {
            const f4_t aG = nt ? accG1 : accG0;
            const int col = w * 32 + nt * 16 + c15;
            #pragma unroll
            for (int q = 0; q < 4; ++q) {
                const int r = rowb + q;
                float gh2 = __expf(-fmaxf(aG[q] + sh_bgh[col], 0.f));
                float hdv = gh2 * sh_h[r][col];
                hd2[nt][q] = hdv;
                sA_hd[((size_t)w * 64 + (((col & 31) >> 3) << 4) + r) * 8 + (col & 7)]
                    = (short)f2bf(hdv);
            }
        }
        __syncthreads();

        f4_t accZ[2] = {accP[0][0], accP[0][1]};
        f4_t accR[2] = {accP[1][0], accP[1][1]};
        #pragma unroll
        for (int kt = 0; kt < 8; ++kt) {
            bf8_t hf = *(const bf8_t*)&sA_hd[(kt * 64 + lane) * 8];
            #pragma unroll
            for (int nt = 0; nt < 2; ++nt) {
                const int ntG = 2 * w + nt;
                accZ[nt] = MFp(hf, BA(whp + 0 * 65536, ntG, 8, kt, lane), accZ[nt]);
                accR[nt] = MFp(hf, BA(whp + 1 * 65536, ntG, 8, kt, lane), accR[nt]);
            }
        }
        float zz2[2][4];
        #pragma unroll
        for (int nt = 0; nt < 2; ++nt) {
            const int col = w * 32 + nt * 16 + c15;
            #pragma unroll
            for (int q = 0; q < 4; ++q) {
                const int r = rowb + q;
                float z  = 1.f / (1.f + __expf(-(accZ[nt][q] + sh_bg[0][col])));
                float rv = 1.f / (1.f + __expf(-(accR[nt][q] + sh_bg[1][col])));
                zz2[nt][q] = z;
                sA_rhd[((size_t)w * 64 + (((col & 31) >> 3) << 4) + r) * 8 + (col & 7)]
                    = (short)f2bf(rv * hd2[nt][q]);
            }
        }
        __syncthreads();

        f4_t accH[2] = {accP[2][0], accP[2][1]};
        #pragma unroll
        for (int kt = 0; kt < 8; ++kt) {
            bf8_t hf = *(const bf8_t*)&sA_rhd[(kt * 64 + lane) * 8];
            #pragma unroll
            for (int nt = 0; nt < 2; ++nt)
                accH[nt] = MFp(hf, BA(whp + 2 * 65536, 2 * w + nt, 8, kt, lane), accH[nt]);
        }
        #pragma unroll
        for (int nt = 0; nt < 2; ++nt) {
            const int col = w * 32 + nt * 16 + c15;
            #pragma unroll
            for (int q = 0; q < 4; ++q) {
                const int r = rowb + q;
                float pre = accH[nt][q] + sh_bg[2][col];
                float a = fabsf(pre), e = __expf(-2.f * a);
                float th = copysignf((1.f - e) / (1.f + e), pre);
                sh_h[r][col] = (1.f - zz2[nt][q]) * hd2[nt][q] + zz2[nt][q] * th;
            }
        }
        __syncthreads();
    }

    if (tid < BB) {
        float s2 = 0.f;
        for (int k = 0; k < Hn; ++k) s2 = fmaf(sh_h[tid][k], W_cls[k], s2);
        out[b0 + tid] = s2 + b_cls[0];
    }
}

extern "C" void kernel_launch(void* const* d_in, const int* in_sizes, int n_in,
                              void* d_out, int out_size, void* d_ws, size_t ws_size,
                              hipStream_t stream) {
    const float* X      = (const float*)d_in[0];
    const float* M      = (const float*)d_in[1];
    const float* Dl     = (const float*)d_in[2];
    const float* x_mean = (const float*)d_in[3];
    const float* W_gx   = (const float*)d_in[4];
    const float* b_gx   = (const float*)d_in[5];
    const float* W_gh   = (const float*)d_in[6];
    const float* b_gh   = (const float*)d_in[7];
    const float* W_x    = (const float*)d_in[8];
    const float* W_h    = (const float*)d_in[9];
    const float* W_m    = (const float*)d_in[10];
    const float* b_g    = (const float*)d_in[11];
    const float* W_cls  = (const float*)d_in[12];
    const float* b_cls  = (const float*)d_in[13];
    float* out = (float*)d_out;
    short* pk  = (short*)d_ws;

    hipLaunchKernelGGL(pack_weights, dim3((PACK_SLOTS + 255) / 256), dim3(256), 0, stream,
                       W_gx, W_gh, W_x, W_h, W_m, pk);

    if (ws_size >= WS_NEED) {
        float*          gxbuf = (float*)((char*)d_ws + GX_OFF);
        unsigned short* ghbuf = (unsigned short*)((char*)d_ws + GH_OFF);
        hipLaunchKernelGGL(grud_prepass, dim3(NBLK * Tn), dim3(256), 0, stream,
                           Dl, b_gx, b_gh, pk, gxbuf, ghbuf);
        hipLaunchKernelGGL(grud_rec12, dim3(NBLK), dim3(1024), 0, stream,
                           X, M, x_mean, b_g, W_cls, b_cls, pk, gxbuf, ghbuf, out);
    } else {
        hipLaunchKernelGGL(grud_main, dim3(NBLK), dim3(512), 0, stream,
                           X, M, Dl, x_mean, b_gx, b_gh, b_g, W_cls, b_cls, pk, out);
    }
}

// Round 13
// 1041.305 us; speedup vs baseline: 4.1189x; 2.5077x over previous
//
#include <hip/hip_runtime.h>

// GRU-D, round 13.
// Tier A (ws >= ~186MB): pack -> prepass(gx,gh) -> xhat scan -> per-chunk
//   {pgemm_c (P = xhat@W_x + m@W_m + b_g, bf16 C/D-frag layout) -> rec13}.
//   rec13's t-loop keeps only the h-recurrence: hd build -> z/r GEMM (W_h[0]
//   streamed, W_h[1] LDS) -> h~ GEMM (W_h[2] streamed) -> blend. 48 MFMA/wave
//   /step (was 72), no x-side weight streams, no x-hat builder.
//   P buffer (100.7MB, Tc=128) overlaps the dead gx region; h-state persists
//   in ws between the two chunk launches.
// Tier B (ws >= 101.7MB, proven): rec8 fallback (2243us).

constexpr int Bn = 512, Tn = 256, Dn = 64, Hn = 256;
constexpr int BB = 16, NBLK = Bn / BB;   // 32 blocks
constexpr int TC = 128;                  // P chunk length

typedef __attribute__((ext_vector_type(8))) short bf8_t;
typedef __attribute__((ext_vector_type(4))) float f4_t;

constexpr size_t OFF_WH  = 0;
constexpr size_t OFF_WX  = 196608;
constexpr size_t OFF_WM  = 245760;
constexpr size_t OFF_WGH = 294912;
constexpr size_t OFF_WGX = 311296;
constexpr int    PACK_SLOTS = 39424;

// Tier B layout (proven)
constexpr size_t GX_OFF  = (size_t)1 << 20;
constexpr size_t GH_OFF  = GX_OFF + (size_t)Bn * Tn * Dn * 4;
constexpr size_t WS_NEED = GH_OFF + (size_t)Bn * Tn * Hn * 2;    // 101,711,872

// Tier A layout
constexpr size_t GH2_OFF = (size_t)1 << 20;                       // gh bf16, 67.1MB
constexpr size_t GX2_OFF = GH2_OFF + (size_t)Bn * Tn * Hn * 2;    // gx f32, 33.5MB (dead after xhat)
constexpr size_t P2_OFF  = GX2_OFF;                               // P bf16 chunk, 100.7MB (overlaps gx)
constexpr size_t P2_SZ   = (size_t)3 * Bn * TC * Hn * 2;
constexpr size_t XH2_OFF = P2_OFF + P2_SZ;                        // xhat bf16, 16.8MB
constexpr size_t HST_OFF = XH2_OFF + (size_t)Bn * Tn * Dn * 2;    // h state bf16, 0.26MB
constexpr size_t WS_NEED3 = HST_OFF + (size_t)Bn * Hn * 2;        // ~185.9MB

__device__ __forceinline__ unsigned short f2bf(float x) {
    union { float f; unsigned int u; } v; v.f = x;
    unsigned int r = (v.u + 0x7fffu + ((v.u >> 16) & 1u)) >> 16;   // RNE
    return (unsigned short)r;
}
__device__ __forceinline__ float bf2f(unsigned short u) {
    union { unsigned int i; float f; } v; v.i = ((unsigned int)u) << 16; return v.f;
}
__device__ __forceinline__ bf8_t LD8(const short* p) { return *(const bf8_t*)p; }
__device__ __forceinline__ f4_t MF(bf8_t a, bf8_t b, f4_t c) {
    return __builtin_amdgcn_mfma_f32_16x16x32_bf16(a, b, c, 0, 0, 0);
}
__device__ __forceinline__ f4_t MFp(bf8_t a, const short* bp, f4_t c) {
    return MF(a, LD8(bp), c);
}
__device__ __forceinline__ const short* BA(const short* p, int ntG, int KT, int kt, int lane) {
    return p + (((size_t)ntG * KT + kt) * 64 + lane) * 8;
}
__device__ __forceinline__ void lds_sync() {
    __builtin_amdgcn_sched_barrier(0);
    asm volatile("s_waitcnt lgkmcnt(0)" ::: "memory");
    __builtin_amdgcn_s_barrier();
    __builtin_amdgcn_sched_barrier(0);
}

// ---------------------------------------------------------------------------
// pack_weights (proven)
// ---------------------------------------------------------------------------
__global__ __launch_bounds__(256) void pack_weights(
    const float* __restrict__ W_gx, const float* __restrict__ W_gh,
    const float* __restrict__ W_x,  const float* __restrict__ W_h,
    const float* __restrict__ W_m,  short* __restrict__ out)
{
    const int slot = blockIdx.x * 256 + threadIdx.x;
    if (slot >= PACK_SLOTS) return;

    const float* w; int ldn, l, kt, j, kbase;
    if (slot < 24576) {
        int g = slot >> 13, rem = slot & 8191;
        int ntG = rem >> 9, r2 = rem & 511;
        kt = r2 >> 6; l = r2 & 63;
        j = ntG * 16 + (l & 15);
        w = W_h + (size_t)g * Hn * Hn; ldn = Hn;
    } else if (slot < 30720) {
        int s = slot - 24576;
        int g = s >> 11, rem = s & 2047;
        int ntG = rem >> 7, r2 = rem & 127;
        kt = r2 >> 6; l = r2 & 63;
        j = ntG * 16 + (l & 15);
        w = W_x + (size_t)g * Dn * Hn; ldn = Hn;
    } else if (slot < 36864) {
        int s = slot - 30720;
        int g = s >> 11, rem = s & 2047;
        int ntG = rem >> 7, r2 = rem & 127;
        kt = r2 >> 6; l = r2 & 63;
        j = ntG * 16 + (l & 15);
        w = W_m + (size_t)g * Dn * Hn; ldn = Hn;
    } else if (slot < 38912) {
        int s = slot - 36864;
        int ntG = s >> 7, r2 = s & 127;
        kt = r2 >> 6; l = r2 & 63;
        j = ntG * 16 + (l & 15);
        w = W_gh; ldn = Hn;
    } else {
        int s = slot - 38912;
        int ntG = s >> 7, r2 = s & 127;
        kt = r2 >> 6; l = r2 & 63;
        j = ntG * 16 + (l & 15);
        w = W_gx; ldn = Dn;
    }
    kbase = kt * 32 + ((l >> 4) << 3);
    bf8_t v;
    #pragma unroll
    for (int i = 0; i < 8; ++i)
        v[i] = (short)f2bf(w[(size_t)(kbase + i) * ldn + j]);
    *(bf8_t*)&out[(size_t)slot * 8] = v;
}

// ---------------------------------------------------------------------------
// prepass (proven): gamma_x f32, gamma_h bf16
// ---------------------------------------------------------------------------
__global__ __launch_bounds__(256) void grud_prepass(
    const float* __restrict__ Dl, const float* __restrict__ b_gx,
    const float* __restrict__ b_gh, const short* __restrict__ pk,
    float* __restrict__ gx, unsigned short* __restrict__ gh)
{
    __shared__ short sDf[2 * 64 * 8];
    const int tid = threadIdx.x, w = tid >> 6, lane = tid & 63;
    const int bt = blockIdx.x >> 8, t = blockIdx.x & 255;
    const int b0 = bt * 16;
    const int c15 = lane & 15, rowb = (lane >> 4) * 4;

    if (w < 2) {
        const int row = lane & 15, cb = w * 32 + ((lane >> 4) << 3);
        const float* p = Dl + ((size_t)(b0 + row) * Tn + t) * Dn + cb;
        float4 a = *(const float4*)p, b = *(const float4*)(p + 4);
        bf8_t v;
        v[0]=(short)f2bf(a.x); v[1]=(short)f2bf(a.y); v[2]=(short)f2bf(a.z); v[3]=(short)f2bf(a.w);
        v[4]=(short)f2bf(b.x); v[5]=(short)f2bf(b.y); v[6]=(short)f2bf(b.z); v[7]=(short)f2bf(b.w);
        *(bf8_t*)&sDf[(w * 64 + lane) * 8] = v;
    }
    __syncthreads();
    bf8_t df0 = *(const bf8_t*)&sDf[lane * 8];
    bf8_t df1 = *(const bf8_t*)&sDf[(64 + lane) * 8];

    #pragma unroll
    for (int i = 0; i < 4; ++i) {
        const int ntG = 4 * w + i;
        f4_t acc = {0.f, 0.f, 0.f, 0.f};
        acc = MFp(df0, BA(pk + OFF_WGH, ntG, 2, 0, lane), acc);
        acc = MFp(df1, BA(pk + OFF_WGH, ntG, 2, 1, lane), acc);
        const int col = ntG * 16 + c15;
        const float bb = b_gh[col];
        #pragma unroll
        for (int q = 0; q < 4; ++q) {
            const int r = rowb + q;
            gh[((size_t)(b0 + r) * Tn + t) * Hn + col] =
                f2bf(__expf(-fmaxf(acc[q] + bb, 0.f)));
        }
    }
    {
        f4_t acc = {0.f, 0.f, 0.f, 0.f};
        acc = MFp(df0, BA(pk + OFF_WGX, w, 2, 0, lane), acc);
        acc = MFp(df1, BA(pk + OFF_WGX, w, 2, 1, lane), acc);
        const int col = w * 16 + c15;
        const float bb = b_gx[col];
        #pragma unroll
        for (int q = 0; q < 4; ++q) {
            const int r = rowb + q;
            gx[((size_t)(b0 + r) * Tn + t) * Dn + col] =
                __expf(-fmaxf(acc[q] + bb, 0.f));
        }
    }
}

// ---------------------------------------------------------------------------
// xhat scan: one thread per (b,d), sequential over t. Writes x_hat bf16.
// ---------------------------------------------------------------------------
__global__ __launch_bounds__(256) void grud_xhat(
    const float* __restrict__ X, const float* __restrict__ M,
    const float* __restrict__ x_mean, const float* __restrict__ gx,
    unsigned short* __restrict__ XH)
{
    const int g = blockIdx.x * 256 + threadIdx.x;   // 32768 threads
    const int b = g >> 6, d = g & 63;
    const float xm = x_mean[d];
    float xp = 0.f;
    const size_t base = (size_t)b * Tn * Dn + d;
    for (int t = 0; t < Tn; ++t) {
        const size_t idx = base + (size_t)t * Dn;
        const float x = X[idx], m = M[idx], gv = gx[idx];
        const float xh = m * x + (1.f - m) * (gv * xp + (1.f - gv) * xm);
        xp = m * x + (1.f - m) * xp;
        XH[idx] = f2bf(xh);
    }
}

// ---------------------------------------------------------------------------
// pgemm chunk: P[btl][g][ntG][lane*4..] = xhat@W_x + m@W_m + b_g (bf16, C/D)
// grid = NBLK * TC; btl = blockIdx.x.
// ---------------------------------------------------------------------------
__global__ __launch_bounds__(256) void grud_pgemm_c(
    const float* __restrict__ M, const unsigned short* __restrict__ XH,
    const float* __restrict__ b_g, const short* __restrict__ pk,
    unsigned short* __restrict__ P, int t0)
{
    const int tid = threadIdx.x, w = tid >> 6, lane = tid & 63;
    const int c15 = lane & 15;
    const int bblk = blockIdx.x >> 7;          // TC = 128
    const int tl = blockIdx.x & (TC - 1);
    const int b0 = bblk * 16, t = t0 + tl;

    const size_t abase = ((size_t)(b0 + (lane & 15)) * Tn + t) * Dn + ((lane >> 4) << 3);
    bf8_t xf[2], mf[2];
    #pragma unroll
    for (int kt = 0; kt < 2; ++kt) {
        uint4 xa = *(const uint4*)&XH[abase + kt * 32];
        union { uint4 u; bf8_t b; } cvt; cvt.u = xa;
        xf[kt] = cvt.b;
        float4 a = *(const float4*)&M[abase + kt * 32];
        float4 b = *(const float4*)&M[abase + kt * 32 + 4];
        bf8_t v;
        v[0]=(short)f2bf(a.x); v[1]=(short)f2bf(a.y); v[2]=(short)f2bf(a.z); v[3]=(short)f2bf(a.w);
        v[4]=(short)f2bf(b.x); v[5]=(short)f2bf(b.y); v[6]=(short)f2bf(b.z); v[7]=(short)f2bf(b.w);
        mf[kt] = v;
    }

    const size_t btl = (size_t)blockIdx.x;     // bblk*TC + tl
    #pragma unroll
    for (int i = 0; i < 12; ++i) {
        const int p = w * 12 + i;
        const int gg = p >> 4, ntG = p & 15;
        f4_t acc = {0.f, 0.f, 0.f, 0.f};
        acc = MFp(xf[0], BA(pk + OFF_WX + (size_t)gg * 16384, ntG, 2, 0, lane), acc);
        acc = MFp(xf[1], BA(pk + OFF_WX + (size_t)gg * 16384, ntG, 2, 1, lane), acc);
        acc = MFp(mf[0], BA(pk + OFF_WM + (size_t)gg * 16384, ntG, 2, 0, lane), acc);
        acc = MFp(mf[1], BA(pk + OFF_WM + (size_t)gg * 16384, ntG, 2, 1, lane), acc);
        const float bb = b_g[gg * Hn + ntG * 16 + c15];
        ushort4 o;
        o.x = f2bf(acc[0] + bb); o.y = f2bf(acc[1] + bb);
        o.z = f2bf(acc[2] + bb); o.w = f2bf(acc[3] + bb);
        *(ushort4*)&P[((btl * 3 + gg) * 16 + ntG) * 256 + lane * 4] = o;
    }
}

// ---------------------------------------------------------------------------
// rec13: h-recurrence only, one TC-chunk per launch. 32 blocks x 512 thr.
// ---------------------------------------------------------------------------
__global__ __launch_bounds__(512, 2) void grud_rec13(
    const float* __restrict__ W_cls, const float* __restrict__ b_cls,
    const short* __restrict__ pk, const unsigned short* __restrict__ gh,
    const unsigned short* __restrict__ P, unsigned short* __restrict__ hst,
    float* __restrict__ out, int t0, int lastc)
{
    __shared__ short sWh1[16 * 8 * 64 * 8];      // 131072 B : W_h[1] B-frags
    __shared__ unsigned short sh_hb[16][264];    //   8448 B : h state (bf16)
    __shared__ short sA_hd[8 * 64 * 8];          //   8192 B
    __shared__ short sA_rhd[8 * 64 * 8];         //   8192 B  => 155904 B

    const int tid = threadIdx.x, w = tid >> 6, lane = tid & 63;
    const int c15 = lane & 15, rowb = (lane >> 4) * 4;
    const int b0 = blockIdx.x * BB;
    unsigned short* hs = hst + (size_t)blockIdx.x * 16 * Hn;

    // W_h[0]/W_h[2] (compiler remats into chains — rec8-proven numerics)
    bf8_t whz[2][8], whh[2][8];
    #pragma unroll
    for (int nt = 0; nt < 2; ++nt)
        #pragma unroll
        for (int kt = 0; kt < 8; ++kt) {
            whz[nt][kt] = LD8(BA(pk + OFF_WH,             2 * w + nt, 8, kt, lane));
            whh[nt][kt] = LD8(BA(pk + OFF_WH + 2 * 65536, 2 * w + nt, 8, kt, lane));
        }
    for (int c = tid; c < 8192; c += 512)
        *(uint4*)&sWh1[c * 8] = *(const uint4*)&pk[OFF_WH + 65536 + (size_t)c * 8];

    float h_cd[2][4];
    if (t0 == 0) {
        for (int i = tid; i < 16 * 264; i += 512) (&sh_hb[0][0])[i] = 0;
        #pragma unroll
        for (int nt = 0; nt < 2; ++nt)
            #pragma unroll
            for (int q = 0; q < 4; ++q) h_cd[nt][q] = 0.f;
    } else {
        for (int i = tid; i < 16 * 256; i += 512)
            sh_hb[i >> 8][i & 255] = hs[i];
        #pragma unroll
        for (int nt = 0; nt < 2; ++nt)
            #pragma unroll
            for (int q = 0; q < 4; ++q)
                h_cd[nt][q] = bf2f(hs[(rowb + q) * Hn + w * 32 + nt * 16 + c15]);
    }

    const size_t ghA_base = ((size_t)(b0 + (lane & 15)) * Tn) * Hn + w * 32 + ((lane >> 4) << 3);
    uint4 gha = *(const uint4*)&gh[ghA_base + (size_t)t0 * Hn];
    unsigned short ghcd[2][4];
    #pragma unroll
    for (int nt = 0; nt < 2; ++nt)
        #pragma unroll
        for (int q = 0; q < 4; ++q)
            ghcd[nt][q] = gh[((size_t)(b0 + rowb + q) * Tn + t0) * Hn + w * 32 + nt * 16 + c15];

    ushort4 pz[2], pr[2], ph[2];
    {
        const size_t pbl = (size_t)blockIdx.x * TC;   // tl = 0
        #pragma unroll
        for (int nt = 0; nt < 2; ++nt) {
            pz[nt] = *(const ushort4*)&P[((pbl * 3 + 0) * 16 + 2 * w + nt) * 256 + lane * 4];
            pr[nt] = *(const ushort4*)&P[((pbl * 3 + 1) * 16 + 2 * w + nt) * 256 + lane * 4];
            ph[nt] = *(const ushort4*)&P[((pbl * 3 + 2) * 16 + 2 * w + nt) * 256 + lane * 4];
        }
    }
    float hd_cd[2][4], zz[2][4];
    const f4_t z4 = {0.f, 0.f, 0.f, 0.f};
    __syncthreads();

    for (int tl = 0; tl < TC; ++tl) {
        const int tnl = (tl + 1 < TC) ? (tl + 1) : (TC - 1);
        const int tn  = t0 + tnl;

        // ===== PH1: hd A-frag build + t+1 prefetch =====
        {
            uint4 hA = *(const uint4*)&sh_hb[lane & 15][w * 32 + ((lane >> 4) << 3)];
            unsigned int ga[4] = {gha.x, gha.y, gha.z, gha.w};
            unsigned int ha[4] = {hA.x, hA.y, hA.z, hA.w};
            bf8_t hv;
            #pragma unroll
            for (int i = 0; i < 8; ++i) {
                float gf = bf2f((unsigned short)((ga[i >> 1] >> ((i & 1) * 16)) & 0xffffu));
                float hf = bf2f((unsigned short)((ha[i >> 1] >> ((i & 1) * 16)) & 0xffffu));
                hv[i] = (short)f2bf(gf * hf);
            }
            *(bf8_t*)&sA_hd[(w * 64 + lane) * 8] = hv;
        }
        #pragma unroll
        for (int nt = 0; nt < 2; ++nt)
            #pragma unroll
            for (int q = 0; q < 4; ++q)
                hd_cd[nt][q] = bf2f(ghcd[nt][q]) * h_cd[nt][q];

        // prefetch t+1 (rides across lgkmcnt-only barriers)
        uint4 gha_n = *(const uint4*)&gh[ghA_base + (size_t)tn * Hn];
        unsigned short ghcd_n[2][4];
        #pragma unroll
        for (int nt = 0; nt < 2; ++nt)
            #pragma unroll
            for (int q = 0; q < 4; ++q)
                ghcd_n[nt][q] = gh[((size_t)(b0 + rowb + q) * Tn + tn) * Hn + w * 32 + nt * 16 + c15];
        ushort4 pz_n[2], pr_n[2], ph_n[2];
        {
            const size_t pbl = (size_t)blockIdx.x * TC + tnl;
            #pragma unroll
            for (int nt = 0; nt < 2; ++nt) {
                pz_n[nt] = *(const ushort4*)&P[((pbl * 3 + 0) * 16 + 2 * w + nt) * 256 + lane * 4];
                pr_n[nt] = *(const ushort4*)&P[((pbl * 3 + 1) * 16 + 2 * w + nt) * 256 + lane * 4];
                ph_n[nt] = *(const ushort4*)&P[((pbl * 3 + 2) * 16 + 2 * w + nt) * 256 + lane * 4];
            }
        }
        lds_sync();   // bar0

        // ===== PH2: z and r gates =====
        f4_t aZ[2] = {z4, z4}, aR[2] = {z4, z4};
        #pragma unroll
        for (int kt = 0; kt < 8; ++kt) {
            bf8_t hf  = LD8(&sA_hd[(kt * 64 + lane) * 8]);
            bf8_t wr0 = LD8(&sWh1[((2 * w + 0) * 8 + kt) * 512 + lane * 8]);
            bf8_t wr1 = LD8(&sWh1[((2 * w + 1) * 8 + kt) * 512 + lane * 8]);
            aZ[0] = MF(hf, whz[0][kt], aZ[0]);
            aZ[1] = MF(hf, whz[1][kt], aZ[1]);
            aR[0] = MF(hf, wr0, aR[0]);
            aR[1] = MF(hf, wr1, aR[1]);
        }
        #pragma unroll
        for (int nt = 0; nt < 2; ++nt) {
            const int col = w * 32 + nt * 16 + c15;
            #pragma unroll
            for (int q = 0; q < 4; ++q) {
                const int r = rowb + q;
                float z  = 1.f / (1.f + __expf(-(aZ[nt][q] + bf2f(((const unsigned short*)&pz[nt])[q]))));
                float rr = 1.f / (1.f + __expf(-(aR[nt][q] + bf2f(((const unsigned short*)&pr[nt])[q]))));
                zz[nt][q] = z;
                sA_rhd[(w * 64 + ((col & 31) >> 3) * 16 + r) * 8 + (col & 7)] =
                    (short)f2bf(rr * hd_cd[nt][q]);
            }
        }
        lds_sync();   // bar1

        // ===== PH3: h_tilde + h update =====
        f4_t aH[2] = {z4, z4};
        #pragma unroll
        for (int kt = 0; kt < 8; ++kt) {
            bf8_t rf = LD8(&sA_rhd[(kt * 64 + lane) * 8]);
            aH[0] = MF(rf, whh[0][kt], aH[0]);
            aH[1] = MF(rf, whh[1][kt], aH[1]);
        }
        #pragma unroll
        for (int nt = 0; nt < 2; ++nt) {
            const int col = w * 32 + nt * 16 + c15;
            #pragma unroll
            for (int q = 0; q < 4; ++q) {
                const int r = rowb + q;
                float pre = aH[nt][q] + bf2f(((const unsigned short*)&ph[nt])[q]);
                float a = fabsf(pre), e = __expf(-2.f * a);
                float th = copysignf((1.f - e) / (1.f + e), pre);
                float hn = (1.f - zz[nt][q]) * hd_cd[nt][q] + zz[nt][q] * th;
                h_cd[nt][q] = hn;
                sh_hb[r][col] = f2bf(hn);
            }
        }
        lds_sync();   // bar2

        gha = gha_n;
        #pragma unroll
        for (int nt = 0; nt < 2; ++nt) {
            #pragma unroll
            for (int q = 0; q < 4; ++q) ghcd[nt][q] = ghcd_n[nt][q];
            pz[nt] = pz_n[nt]; pr[nt] = pr_n[nt]; ph[nt] = ph_n[nt];
        }
    }

    if (!lastc) {
        for (int i = tid; i < 16 * 256; i += 512)
            hs[i] = sh_hb[i >> 8][i & 255];
    } else {
        #pragma unroll
        for (int rr2 = 0; rr2 < 2; ++rr2) {
            const int row = w * 2 + rr2;
            ushort4 hb = *(const ushort4*)&sh_hb[row][lane * 4];
            float4 wv  = *(const float4*)&W_cls[lane * 4];
            float p = bf2f(hb.x) * wv.x + bf2f(hb.y) * wv.y +
                      bf2f(hb.z) * wv.z + bf2f(hb.w) * wv.w;
            #pragma unroll
            for (int o = 32; o > 0; o >>= 1) p += __shfl_down(p, o, 64);
            if (lane == 0) out[b0 + row] = p + b_cls[0];
        }
    }
}

// ---------------------------------------------------------------------------
// Tier B fallback: rec8 (proven 2243us)
// ---------------------------------------------------------------------------
__global__ __launch_bounds__(512, 2) void grud_rec8(
    const float* __restrict__ X, const float* __restrict__ M,
    const float* __restrict__ x_mean, const float* __restrict__ b_g,
    const float* __restrict__ W_cls, const float* __restrict__ b_cls,
    const short* __restrict__ pk, const float* __restrict__ gx,
    const unsigned short* __restrict__ gh, float* __restrict__ out)
{
    __shared__ short sWh1[16 * 8 * 64 * 8];
    __shared__ unsigned short sh_hb[16][264];
    __shared__ short sA_xh[2 * 64 * 8];
    __shared__ short sA_m [2 * 64 * 8];
    __shared__ short sA_hd[8 * 64 * 8];
    __shared__ short sA_rhd[8 * 64 * 8];

    const int tid = threadIdx.x, w = tid >> 6, lane = tid & 63;
    const int c15 = lane & 15, rowb = (lane >> 4) * 4;
    const int b0 = blockIdx.x * BB;

    bf8_t whz[2][8], whh[2][8];
    #pragma unroll
    for (int nt = 0; nt < 2; ++nt)
        #pragma unroll
        for (int kt = 0; kt < 8; ++kt) {
            whz[nt][kt] = LD8(BA(pk + OFF_WH,             2 * w + nt, 8, kt, lane));
            whh[nt][kt] = LD8(BA(pk + OFF_WH + 2 * 65536, 2 * w + nt, 8, kt, lane));
        }
    for (int c = tid; c < 8192; c += 512)
        *(uint4*)&sWh1[c * 8] = *(const uint4*)&pk[OFF_WH + 65536 + (size_t)c * 8];
    for (int i = tid; i < 16 * 264; i += 512) (&sh_hb[0][0])[i] = 0;

    const float bz[2] = { b_g[0 * Hn + w * 32 + c15], b_g[0 * Hn + w * 32 + 16 + c15] };
    const float brr[2]= { b_g[1 * Hn + w * 32 + c15], b_g[1 * Hn + w * 32 + 16 + c15] };
    const float bh[2] = { b_g[2 * Hn + w * 32 + c15], b_g[2 * Hn + w * 32 + 16 + c15] };

    const int s    = w * 32 + (lane & 31);
    const int kt2  = s >> 7, fl = (s >> 1) & 63, half = s & 1;
    const int brow = fl & 15, bcol = kt2 * 32 + ((fl >> 4) << 3) + half * 4;
    const size_t brow_base = ((size_t)(b0 + brow) * Tn) * Dn + bcol;

    float xb[4] = {0.f, 0.f, 0.f, 0.f};
    float xp[4] = {0.f, 0.f, 0.f, 0.f};
    float4 mv, xv = {0,0,0,0}, gxv = {0,0,0,0};
    if (lane < 32) {
        xb[0]=x_mean[bcol]; xb[1]=x_mean[bcol+1]; xb[2]=x_mean[bcol+2]; xb[3]=x_mean[bcol+3];
        xv  = *(const float4*)&X[brow_base];
        gxv = *(const float4*)&gx[brow_base];
    }
    mv = *(const float4*)&M[brow_base];

    const size_t ghA_base  = ((size_t)(b0 + (lane & 15)) * Tn) * Hn + w * 32 + ((lane >> 4) << 3);
    uint4 gha = *(const uint4*)&gh[ghA_base];
    unsigned short ghcd[2][4];
    #pragma unroll
    for (int nt = 0; nt < 2; ++nt)
        #pragma unroll
        for (int q = 0; q < 4; ++q)
            ghcd[nt][q] = gh[((size_t)(b0 + rowb + q) * Tn) * Hn + w * 32 + nt * 16 + c15];

    float h_cd[2][4] = {{0.f,0.f,0.f,0.f},{0.f,0.f,0.f,0.f}};
    float hd_cd[2][4], zz[2][4];
    const f4_t z4 = {0.f, 0.f, 0.f, 0.f};
    __syncthreads();

    for (int t = 0; t < Tn; ++t) {
        const int tn = (t + 1 < Tn) ? (t + 1) : (Tn - 1);

        {
            uint4 hA = *(const uint4*)&sh_hb[lane & 15][w * 32 + ((lane >> 4) << 3)];
            unsigned int ga[4] = {gha.x, gha.y, gha.z, gha.w};
            unsigned int ha[4] = {hA.x, hA.y, hA.z, hA.w};
            bf8_t hv;
            #pragma unroll
            for (int i = 0; i < 8; ++i) {
                float gf = bf2f((unsigned short)((ga[i >> 1] >> ((i & 1) * 16)) & 0xffffu));
                float hf = bf2f((unsigned short)((ha[i >> 1] >> ((i & 1) * 16)) & 0xffffu));
                hv[i] = (short)f2bf(gf * hf);
            }
            *(bf8_t*)&sA_hd[(w * 64 + lane) * 8] = hv;
        }
        #pragma unroll
        for (int nt = 0; nt < 2; ++nt)
            #pragma unroll
            for (int q = 0; q < 4; ++q)
                hd_cd[nt][q] = bf2f(ghcd[nt][q]) * h_cd[nt][q];

        if (lane < 32) {
            float mm[4] = {mv.x, mv.y, mv.z, mv.w};
            float xx[4] = {xv.x, xv.y, xv.z, xv.w};
            float gg[4] = {gxv.x, gxv.y, gxv.z, gxv.w};
            float xh[4];
            #pragma unroll
            for (int j = 0; j < 4; ++j) {
                xh[j] = mm[j] * xx[j] + (1.f - mm[j]) * (gg[j] * xp[j] + (1.f - gg[j]) * xb[j]);
                xp[j] = mm[j] * xx[j] + (1.f - mm[j]) * xp[j];
            }
            uint2 dd;
            dd.x = (unsigned int)f2bf(xh[0]) | ((unsigned int)f2bf(xh[1]) << 16);
            dd.y = (unsigned int)f2bf(xh[2]) | ((unsigned int)f2bf(xh[3]) << 16);
            *(uint2*)&sA_xh[(kt2 * 64 + fl) * 8 + half * 4] = dd;
        } else {
            uint2 dd;
            dd.x = (unsigned int)f2bf(mv.x) | ((unsigned int)f2bf(mv.y) << 16);
            dd.y = (unsigned int)f2bf(mv.z) | ((unsigned int)f2bf(mv.w) << 16);
            *(uint2*)&sA_m[(kt2 * 64 + fl) * 8 + half * 4] = dd;
        }
        {
            const size_t ba = brow_base + (size_t)tn * Dn;
            mv = *(const float4*)&M[ba];
            if (lane < 32) {
                xv  = *(const float4*)&X[ba];
                gxv = *(const float4*)&gx[ba];
            }
            gha = *(const uint4*)&gh[ghA_base + (size_t)tn * Hn];
            #pragma unroll
            for (int nt = 0; nt < 2; ++nt)
                #pragma unroll
                for (int q = 0; q < 4; ++q)
                    ghcd[nt][q] = gh[((size_t)(b0 + rowb + q) * Tn + tn) * Hn + w * 32 + nt * 16 + c15];
        }
        lds_sync();

        bf8_t wxz[2][2], wxr[2][2], wmz[2][2], wmr[2][2];
        #pragma unroll
        for (int nt = 0; nt < 2; ++nt)
            #pragma unroll
            for (int kt = 0; kt < 2; ++kt) {
                wxz[nt][kt] = LD8(BA(pk + OFF_WX,         2 * w + nt, 2, kt, lane));
                wxr[nt][kt] = LD8(BA(pk + OFF_WX + 16384, 2 * w + nt, 2, kt, lane));
                wmz[nt][kt] = LD8(BA(pk + OFF_WM,         2 * w + nt, 2, kt, lane));
                wmr[nt][kt] = LD8(BA(pk + OFF_WM + 16384, 2 * w + nt, 2, kt, lane));
            }
        bf8_t xf0 = LD8(&sA_xh[lane * 8]), xf1 = LD8(&sA_xh[(64 + lane) * 8]);
        bf8_t mf0 = LD8(&sA_m [lane * 8]), mf1 = LD8(&sA_m [(64 + lane) * 8]);

        f4_t aZ[2] = {z4, z4}, aR[2] = {z4, z4};
        #pragma unroll
        for (int kt = 0; kt < 8; ++kt) {
            bf8_t hf  = LD8(&sA_hd[(kt * 64 + lane) * 8]);
            bf8_t wr0 = LD8(&sWh1[((2 * w + 0) * 8 + kt) * 512 + lane * 8]);
            bf8_t wr1 = LD8(&sWh1[((2 * w + 1) * 8 + kt) * 512 + lane * 8]);
            aZ[0] = MF(hf, whz[0][kt], aZ[0]);
            aZ[1] = MF(hf, whz[1][kt], aZ[1]);
            aR[0] = MF(hf, wr0, aR[0]);
            aR[1] = MF(hf, wr1, aR[1]);
        }
        #pragma unroll
        for (int nt = 0; nt < 2; ++nt) {
            aZ[nt] = MF(xf0, wxz[nt][0], aZ[nt]); aZ[nt] = MF(xf1, wxz[nt][1], aZ[nt]);
            aZ[nt] = MF(mf0, wmz[nt][0], aZ[nt]); aZ[nt] = MF(mf1, wmz[nt][1], aZ[nt]);
            aR[nt] = MF(xf0, wxr[nt][0], aR[nt]); aR[nt] = MF(xf1, wxr[nt][1], aR[nt]);
            aR[nt] = MF(mf0, wmr[nt][0], aR[nt]); aR[nt] = MF(mf1, wmr[nt][1], aR[nt]);
        }
        bf8_t wxh[2][2], wmh[2][2];
        #pragma unroll
        for (int nt = 0; nt < 2; ++nt)
            #pragma unroll
            for (int kt = 0; kt < 2; ++kt) {
                wxh[nt][kt] = LD8(BA(pk + OFF_WX + 32768, 2 * w + nt, 2, kt, lane));
                wmh[nt][kt] = LD8(BA(pk + OFF_WM + 32768, 2 * w + nt, 2, kt, lane));
            }
        #pragma unroll
        for (int nt = 0; nt < 2; ++nt) {
            const int col = w * 32 + nt * 16 + c15;
            #pragma unroll
            for (int q = 0; q < 4; ++q) {
                const int r = rowb + q;
                float z  = 1.f / (1.f + __expf(-(aZ[nt][q] + bz[nt])));
                float rr = 1.f / (1.f + __expf(-(aR[nt][q] + brr[nt])));
                zz[nt][q] = z;
                sA_rhd[(w * 64 + ((col & 31) >> 3) * 16 + r) * 8 + (col & 7)] =
                    (short)f2bf(rr * hd_cd[nt][q]);
            }
        }
        lds_sync();

        f4_t aH[2] = {z4, z4};
        #pragma unroll
        for (int kt = 0; kt < 8; ++kt) {
            bf8_t rf = LD8(&sA_rhd[(kt * 64 + lane) * 8]);
            aH[0] = MF(rf, whh[0][kt], aH[0]);
            aH[1] = MF(rf, whh[1][kt], aH[1]);
        }
        #pragma unroll
        for (int nt = 0; nt < 2; ++nt) {
            aH[nt] = MF(xf0, wxh[nt][0], aH[nt]); aH[nt] = MF(xf1, wxh[nt][1], aH[nt]);
            aH[nt] = MF(mf0, wmh[nt][0], aH[nt]); aH[nt] = MF(mf1, wmh[nt][1], aH[nt]);
        }
        #pragma unroll
        for (int nt = 0; nt < 2; ++nt) {
            const int col = w * 32 + nt * 16 + c15;
            #pragma unroll
            for (int q = 0; q < 4; ++q) {
                const int r = rowb + q;
                float pre = aH[nt][q] + bh[nt];
                float a = fabsf(pre), e = __expf(-2.f * a);
                float th = copysignf((1.f - e) / (1.f + e), pre);
                float hn = (1.f - zz[nt][q]) * hd_cd[nt][q] + zz[nt][q] * th;
                h_cd[nt][q] = hn;
                sh_hb[r][col] = f2bf(hn);
            }
        }
        lds_sync();
    }

    #pragma unroll
    for (int rr2 = 0; rr2 < 2; ++rr2) {
        const int row = w * 2 + rr2;
        ushort4 hb = *(const ushort4*)&sh_hb[row][lane * 4];
        float4 wv  = *(const float4*)&W_cls[lane * 4];
        float p = bf2f(hb.x) * wv.x + bf2f(hb.y) * wv.y +
                  bf2f(hb.z) * wv.z + bf2f(hb.w) * wv.w;
        #pragma unroll
        for (int o = 32; o > 0; o >>= 1) p += __shfl_down(p, o, 64);
        if (lane == 0) out[b0 + row] = p + b_cls[0];
    }
}

extern "C" void kernel_launch(void* const* d_in, const int* in_sizes, int n_in,
                              void* d_out, int out_size, void* d_ws, size_t ws_size,
                              hipStream_t stream) {
    const float* X      = (const float*)d_in[0];
    const float* M      = (const float*)d_in[1];
    const float* Dl     = (const float*)d_in[2];
    const float* x_mean = (const float*)d_in[3];
    const float* W_gx   = (const float*)d_in[4];
    const float* b_gx   = (const float*)d_in[5];
    const float* W_gh   = (const float*)d_in[6];
    const float* b_gh   = (const float*)d_in[7];
    const float* W_x    = (const float*)d_in[8];
    const float* W_h    = (const float*)d_in[9];
    const float* W_m    = (const float*)d_in[10];
    const float* b_g    = (const float*)d_in[11];
    const float* W_cls  = (const float*)d_in[12];
    const float* b_cls  = (const float*)d_in[13];
    float* out = (float*)d_out;
    short* pk  = (short*)d_ws;

    hipLaunchKernelGGL(pack_weights, dim3((PACK_SLOTS + 255) / 256), dim3(256), 0, stream,
                       W_gx, W_gh, W_x, W_h, W_m, pk);

    if (ws_size >= WS_NEED3) {
        unsigned short* gh2 = (unsigned short*)((char*)d_ws + GH2_OFF);
        float*          gx2 = (float*)((char*)d_ws + GX2_OFF);
        unsigned short* P2  = (unsigned short*)((char*)d_ws + P2_OFF);
        unsigned short* xh2 = (unsigned short*)((char*)d_ws + XH2_OFF);
        unsigned short* hst = (unsigned short*)((char*)d_ws + HST_OFF);

        hipLaunchKernelGGL(grud_prepass, dim3(NBLK * Tn), dim3(256), 0, stream,
                           Dl, b_gx, b_gh, pk, gx2, gh2);
        hipLaunchKernelGGL(grud_xhat, dim3(Bn * Dn / 256), dim3(256), 0, stream,
                           X, M, x_mean, gx2, xh2);
        for (int c = 0; c < Tn / TC; ++c) {
            hipLaunchKernelGGL(grud_pgemm_c, dim3(NBLK * TC), dim3(256), 0, stream,
                               M, xh2, b_g, pk, P2, c * TC);
            hipLaunchKernelGGL(grud_rec13, dim3(NBLK), dim3(512), 0, stream,
                               W_cls, b_cls, pk, gh2, P2, hst, out,
                               c * TC, (c == Tn / TC - 1) ? 1 : 0);
        }
    } else {
        float*          gxbuf = (float*)((char*)d_ws + GX_OFF);
        unsigned short* ghbuf = (unsigned short*)((char*)d_ws + GH_OFF);
        hipLaunchKernelGGL(grud_prepass, dim3(NBLK * Tn), dim3(256), 0, stream,
                           Dl, b_gx, b_gh, pk, gxbuf, ghbuf);
        hipLaunchKernelGGL(grud_rec8, dim3(NBLK), dim3(512), 0, stream,
                           X, M, x_mean, b_g, W_cls, b_cls, pk, gxbuf, ghbuf, out);
    }
}